// Round 8
// baseline (391.665 us; speedup 1.0000x reference)
//
#include <hip/hip_runtime.h>
#include <hip/hip_bf16.h>
#include <math.h>

typedef __hip_bfloat16  bf16;
typedef __hip_bfloat162 bf162;
typedef __attribute__((ext_vector_type(8))) short short8;   // 8 bf16 = 4 VGPRs
typedef __attribute__((ext_vector_type(4))) float floatx4;  // MFMA acc
typedef __attribute__((ext_vector_type(2))) float floatx2;  // packed f32 (v_pk_fma_f32)

#define BSZ     128
#define NBMAX   512
#define PACHUNK 4096   // 36KB LDS in partA -> 4 blocks/CU

__device__ inline float4 bf4_to_f4(uint2 v) {
  float2 lo = __bfloat1622float2(*(bf162*)&v.x);
  float2 hi = __bfloat1622float2(*(bf162*)&v.y);
  return make_float4(lo.x, lo.y, hi.x, hi.y);
}
__device__ inline uint2 f4_to_bf4(float4 v) {
  bf162 lo = __float22bfloat162_rn(make_float2(v.x, v.y));
  bf162 hi = __float22bfloat162_rn(make_float2(v.z, v.w));
  uint2 r;
  r.x = *(unsigned*)&lo;
  r.y = *(unsigned*)&hi;
  return r;
}
// one bf162 word -> packed float2 {lo, hi}
__device__ inline floatx2 bf2_to_f2(unsigned u) {
  floatx2 r;
  r.x = __uint_as_float(u << 16);
  r.y = __uint_as_float(u & 0xffff0000u);
  return r;
}

// ---------------- bucket histogram: LDS-privatized, 1 global atomic per bucket per block ----------------
__global__ __launch_bounds__(256) void k_bhist(const int* __restrict__ eiIn, const int* __restrict__ eiOut,
                                               int E, int* __restrict__ bcnt, int NB) {
  __shared__ int h[NBMAX];
  const int t = threadIdx.x;
  const int set = blockIdx.y;
  const int* dst = (set ? eiOut : eiIn) + E;
  for (int i = t; i < NB; i += 256) h[i] = 0;
  __syncthreads();
  const int base = blockIdx.x * PACHUNK;
  const int m = min(PACHUNK, E - base);
  #pragma unroll 4
  for (int r = 0; r < PACHUNK / 256; ++r) {
    int i = r * 256 + t;
    if (i < m) atomicAdd(&h[dst[base + i] >> 7], 1);
  }
  __syncthreads();
  for (int i = t; i < NB; i += 256) {
    int c = h[i];
    if (c) atomicAdd(&bcnt[set * NBMAX + i], c);
  }
}

// ---------------- bucket scan: exclusive prefix over NB buckets -> BO, bcur ----------------
__global__ __launch_bounds__(64) void k_bscan(const int* __restrict__ bcnt,
                                              int* __restrict__ BO, int* __restrict__ bcur, int NB) {
  const int set = blockIdx.x;
  const int t = threadIdx.x;
  int carry = 0;
  for (int base = 0; base < NB; base += 64) {
    int idx = base + t;
    int v = (idx < NB) ? bcnt[set * NBMAX + idx] : 0;
    int incl = v;
    #pragma unroll
    for (int d = 1; d < 64; d <<= 1) {
      int u = __shfl_up(incl, d, 64);
      if (t >= d) incl += u;
    }
    if (idx < NB) {
      int e = carry + incl - v;
      BO[set * NBMAX + idx]   = e;
      bcur[set * NBMAX + idx] = e;
    }
    carry += __shfl(incl, 63, 64);
  }
}

// ---------------- partA: counting-sort edges into bucket-contiguous staging ----------------
__global__ __launch_bounds__(256) void k_partA(const int* __restrict__ eiIn, const float* __restrict__ ewIn,
                                               const int* __restrict__ eiOut, const float* __restrict__ ewOut,
                                               int E, int* __restrict__ bucketCur,
                                               int2* __restrict__ sI, int2* __restrict__ sO, int NB) {
  __shared__ int2 staged[PACHUNK];
  __shared__ int cnt[NBMAX];
  __shared__ int sb[NBMAX];
  const int t = threadIdx.x;
  const int set = blockIdx.y;
  const int*   ei = set ? eiOut : eiIn;
  const float* ew = set ? ewOut : ewIn;
  int2* stg  = set ? sO : sI;
  int*  bcur = bucketCur + set * NBMAX;
  const int base = blockIdx.x * PACHUNK;
  const int m = min(PACHUNK, E - base);
  for (int b = t; b < NB; b += 256) cnt[b] = 0;
  __syncthreads();
  #pragma unroll 4
  for (int r = 0; r < PACHUNK / 256; ++r) {
    int i = r * 256 + t;
    if (i < m) atomicAdd(&cnt[ei[E + base + i] >> 7], 1);
  }
  __syncthreads();
  if (t < 64) {
    int carry = 0;
    int nch = (NB + 63) >> 6;
    for (int c = 0; c < nch; ++c) {
      int idx = c * 64 + t;
      int v = (idx < NB) ? cnt[idx] : 0;
      int incl = v;
      #pragma unroll
      for (int d = 1; d < 64; d <<= 1) {
        int u = __shfl_up(incl, d, 64);
        if (t >= d) incl += u;
      }
      if (idx < NB) sb[idx] = carry + incl - v;
      carry += __shfl(incl, 63, 64);
    }
  }
  __syncthreads();
  for (int b = t; b < NB; b += 256) {
    int c = cnt[b];
    if (c > 0) cnt[b] = atomicAdd(&bcur[b], c) - sb[b];
  }
  __syncthreads();
  #pragma unroll 4
  for (int r = 0; r < PACHUNK / 256; ++r) {
    int i = r * 256 + t;
    if (i < m) {
      int src = ei[base + i];
      int dst = ei[E + base + i];
      float w = ew[base + i];
      int b = dst >> 7;
      int rank = atomicAdd(&sb[b], 1);
      staged[rank] = make_int2(src | ((dst & 127) << 16) | (b << 23), __float_as_int(w));
    }
  }
  __syncthreads();
  #pragma unroll 4
  for (int r = 0; r < PACHUNK / 256; ++r) {
    int j = r * 256 + t;
    if (j < m) {
      int2 p = staged[j];
      int b = ((unsigned)p.x) >> 23;
      stg[cnt[b] + j] = p;
    }
  }
}

// ---------------- partB: bucket staging -> per-node offsets (LDS scan) + final CSR order ----------------
__global__ __launch_bounds__(256) void k_partB(const int* __restrict__ BO, const int* __restrict__ bcur,
                                               const int2* __restrict__ sI, const int2* __restrict__ sO,
                                               int2* __restrict__ eI, int2* __restrict__ eO,
                                               int* __restrict__ offsI, int* __restrict__ offsO, int N) {
  __shared__ int cnt[BSZ];
  __shared__ int excl[BSZ];
  __shared__ int cur[BSZ];
  const int t = threadIdx.x;
  const int b = blockIdx.x;
  const int set = blockIdx.y;
  const int2* stg = set ? sO : sI;
  int2* out = set ? eO : eI;
  int*  offs = set ? offsO : offsI;
  const int nlo = b << 7;
  const int nodes = min(BSZ, N - nlo);
  const int lo = BO[set * NBMAX + b];
  const int hi = bcur[set * NBMAX + b];   // post-partA cursor == bucket end
  if (t < BSZ) cnt[t] = 0;
  __syncthreads();
  for (int i = lo + t; i < hi; i += 256) atomicAdd(&cnt[(stg[i].x >> 16) & 127], 1);
  __syncthreads();
  if (t < 64) {
    int v0 = cnt[t];
    int i0 = v0;
    #pragma unroll
    for (int d = 1; d < 64; d <<= 1) { int u = __shfl_up(i0, d, 64); if (t >= d) i0 += u; }
    int v1 = cnt[64 + t];
    int i1 = v1;
    #pragma unroll
    for (int d = 1; d < 64; d <<= 1) { int u = __shfl_up(i1, d, 64); if (t >= d) i1 += u; }
    int tot0 = __shfl(i0, 63, 64);
    excl[t]      = i0 - v0;
    excl[64 + t] = tot0 + i1 - v1;
  }
  __syncthreads();
  if (t < BSZ) cur[t] = lo + excl[t];
  if (t < nodes) offs[nlo + t] = lo + excl[t];
  if (b == gridDim.x - 1 && t == 0) offs[N] = hi;
  __syncthreads();
  for (int i = lo + t; i < hi; i += 256) {
    int2 p = stg[i];
    int dl = (p.x >> 16) & 127;
    int pos = atomicAdd(&cur[dl], 1);
    out[pos] = make_int2(p.x & 0xffff, p.y);
  }
}

// ---------------- pack all weights (direct from inputs, summed inline) + bias prep ----------------
// P1's K dimension is PERMUTED to match the LDS layout the fused mf01 kernel writes:
// physical k position p holds logical k = (p&7)*16 + (p>>3).
__device__ inline void pack_one(const float* __restrict__ W, bf16* __restrict__ P,
                                int id, int NT, int DO) {
  int lane = id & 63;
  int tile = id >> 6;
  int nt = tile % NT, kt = tile / NT;
  int col  = nt * 16 + (lane & 15);
  int krow = kt * 32 + (lane >> 4) * 8;
  bf16* dst = P + (size_t)id * 8;
  #pragma unroll
  for (int j = 0; j < 8; ++j) dst[j] = __float2bfloat16(W[(size_t)(krow + j) * DO + col]);
}
__global__ void k_packall(const float* __restrict__ Wmi0, const float* __restrict__ Wmo0,
                          const float* __restrict__ Ws0,
                          const float* __restrict__ Wmi1, const float* __restrict__ Wmo1,
                          const float* __restrict__ Ws1,
                          const float* __restrict__ resW, const float* __restrict__ Wd,
                          const float* __restrict__ bmi0, const float* __restrict__ bsi0,
                          const float* __restrict__ bmo0, const float* __restrict__ bso0,
                          const float* __restrict__ bmi1, const float* __restrict__ bsi1,
                          const float* __restrict__ bmo1, const float* __restrict__ bso1,
                          bf16* __restrict__ P0, bf16* __restrict__ P1, bf16* __restrict__ Pd,
                          float* __restrict__ bi0, float* __restrict__ bo0,
                          float* __restrict__ bi1, float* __restrict__ bo1) {
  int id = blockIdx.x * blockDim.x + threadIdx.x;
  const int T0 = 8 * 8 * 64;    // 256x128 (stacked [Wmi0+Ws0 ; Wmo0+Ws0])
  const int T1 = 4 * 12 * 64;   // 128x192 ([Wmi1+Ws1 | Wmo1+Ws1 | resW]), K permuted
  const int Td = 2 * 8 * 64;    // 64x128
  if (id < T0) {
    int lane = id & 63, tile = id >> 6;
    int nt = tile % 8, kt = tile / 8;
    int col  = nt * 16 + (lane & 15);
    int krow = kt * 32 + (lane >> 4) * 8;
    bf16* dst = P0 + (size_t)id * 8;
    #pragma unroll
    for (int j = 0; j < 8; ++j) {
      int r = krow + j;
      float v = (r < 128 ? Wmi0[r * 128 + col] : Wmo0[(r - 128) * 128 + col])
              + Ws0[(r & 127) * 128 + col];
      dst[j] = __float2bfloat16(v);
    }
  } else if (id < T0 + T1) {
    int id1 = id - T0;
    int lane = id1 & 63, tile = id1 >> 6;
    int nt = tile % 12, kt = tile / 12;
    int col  = nt * 16 + (lane & 15);
    int krow = kt * 32 + (lane >> 4) * 8;
    bf16* dst = P1 + (size_t)id1 * 8;
    #pragma unroll
    for (int j = 0; j < 8; ++j) {
      int kp = krow + j;
      int k = ((kp & 7) << 4) + (kp >> 3);   // inverse of mf01's LDS column permutation
      float v;
      if (col < 64)       v = Wmi1[k * 64 + col]       + Ws1[k * 64 + col];
      else if (col < 128) v = Wmo1[k * 64 + col - 64]  + Ws1[k * 64 + col - 64];
      else                v = resW[k * 64 + col - 128];
      dst[j] = __float2bfloat16(v);
    }
  } else if (id < T0 + T1 + Td) {
    pack_one(Wd, Pd, id - T0 - T1, 8, 128);
  } else {
    int j = id - (T0 + T1 + Td);
    if (j < 128) { bi0[j] = bmi0[j] + bsi0[j]; bo0[j] = bmo0[j] + bso0[j]; }
    if (j < 64)  { bi1[j] = bmi1[j] + bsi1[j]; bo1[j] = bmo1[j] + bso1[j]; }
  }
}

// ---------------- h0 table: bf16(x + pe), SLICE-MAJOR [4][N][32] (64B rows) ----------------
__global__ void k_prep0(const float* __restrict__ x, const float* __restrict__ pe,
                        bf16* __restrict__ h0s, int N) {
  int i = blockIdx.x * blockDim.x + threadIdx.x;
  if (i >= N * 128) return;
  int c = i & 31;
  int t = i >> 5;          // = s*N + n
  int s = t / N;
  int n = t - s * N;
  int d = s * 32 + c;
  h0s[i] = __float2bfloat16(x[(size_t)n * 128 + d] + pe[d]);
}

// ---------------- layer-0 gather, DIM-SLICED (4 x 32-dim slices), FULLY PARALLEL ----------------
// One (node, slice) per wave; 4 waves/block; grid = 8 * ceil(ceil(N/4)/2); blockIdx&7 -> XCD,
// slice = xcd>>1 (3.2MB slice table fits 4MB per-XCD L2). A gather = ONE 64B line (was 4).
// Wave: dir = lane>>5, 4 substreams x 8 lanes x 8B per 64B slice row; pk-fma accumulation.
__global__ __launch_bounds__(256) void k_agg0(const bf16* __restrict__ tbS,
                                              const int* __restrict__ offsI, const int2* __restrict__ eI,
                                              const int* __restrict__ offsO, const int2* __restrict__ eO,
                                              const float* __restrict__ cin, const float* __restrict__ cou,
                                              bf16* __restrict__ aggC, int N) {
  const int b = blockIdx.x;
  const int xcd = b & 7;
  const int slice = xcd >> 1;
  const int half = xcd & 1;
  const int worker = (b >> 3) * 2 + half;
  const int wid = threadIdx.x >> 6;
  const int lane = threadIdx.x & 63;
  const int n = worker * 4 + wid;
  if (n >= N) return;
  const int dir = lane >> 5;
  const int sub = (lane >> 3) & 3;
  const int sl  = lane & 7;
  const int*   offs = dir ? offsO : offsI;
  const int2*  el   = dir ? eO : eI;
  const float* cc   = dir ? cou : cin;
  const char* base = (const char*)tbS + (size_t)slice * N * 64 + sl * 8;
  floatx2 A0 = {0.f, 0.f}, A1 = {0.f, 0.f};
  const int s0 = offs[n], s1 = offs[n + 1];
  int i = s0 + sub;
  for (; i + 12 < s1; i += 16) {
    int2 eA = el[i], eB = el[i + 4], eC = el[i + 8], eD = el[i + 12];
    uint2 vA = *(const uint2*)(base + ((size_t)(unsigned)eA.x << 6));
    uint2 vB = *(const uint2*)(base + ((size_t)(unsigned)eB.x << 6));
    uint2 vC = *(const uint2*)(base + ((size_t)(unsigned)eC.x << 6));
    uint2 vD = *(const uint2*)(base + ((size_t)(unsigned)eD.x << 6));
    float fA = __int_as_float(eA.y), fB = __int_as_float(eB.y);
    float fC = __int_as_float(eC.y), fD = __int_as_float(eD.y);
    floatx2 wA = {fA, fA}, wB = {fB, fB}, wC = {fC, fC}, wD = {fD, fD};
    A0 += wA * bf2_to_f2(vA.x) + wB * bf2_to_f2(vB.x) + wC * bf2_to_f2(vC.x) + wD * bf2_to_f2(vD.x);
    A1 += wA * bf2_to_f2(vA.y) + wB * bf2_to_f2(vB.y) + wC * bf2_to_f2(vC.y) + wD * bf2_to_f2(vD.y);
  }
  for (; i < s1; i += 4) {
    int2 e = el[i];
    uint2 v = *(const uint2*)(base + ((size_t)(unsigned)e.x << 6));
    float f = __int_as_float(e.y);
    floatx2 w2 = {f, f};
    A0 += w2 * bf2_to_f2(v.x);
    A1 += w2 * bf2_to_f2(v.y);
  }
  float a0 = A0.x, a1 = A0.y, a2 = A1.x, a3 = A1.y;
  // reduce over the 4 substreams within each 32-lane half
  a0 += __shfl_xor(a0, 8, 64);  a1 += __shfl_xor(a1, 8, 64);
  a2 += __shfl_xor(a2, 8, 64);  a3 += __shfl_xor(a3, 8, 64);
  a0 += __shfl_xor(a0, 16, 64); a1 += __shfl_xor(a1, 16, 64);
  a2 += __shfl_xor(a2, 16, 64); a3 += __shfl_xor(a3, 16, 64);
  if (sub == 0) {
    float c = cc[n];
    uint2 p = f4_to_bf4(make_float4(c * a0, c * a1, c * a2, c * a3));
    *(uint2*)(aggC + (size_t)n * 256 + dir * 128 + slice * 32 + sl * 4) = p;
  }
}

// ---------------- FUSED layer-0 GEMM + epilogue + layer-1 GEMM ----------------
// GEMM0: aggC(256)@Wp0 -> h1 = tanh(.. + h0), kept in LDS (column-permuted: [row][lc*8+nt]).
// GEMM1: h1(LDS)@Wp1(K-permuted) -> [t1g | t1r]. h1 never touches global memory.
// h0 is slice-major: cols {32np+lc, 32np+16+lc} live in slice np at offsets lc / 16+lc.
__global__ __launch_bounds__(256) void k_mf01(const bf16* __restrict__ A,
                                              const bf16* __restrict__ Wp0,
                                              const bf16* __restrict__ Wp1,
                                              const float* __restrict__ bi, const float* __restrict__ bo,
                                              const float* __restrict__ cin, const float* __restrict__ cou,
                                              const bf16* __restrict__ h0,
                                              bf16* __restrict__ t1g, bf16* __restrict__ t1r, int N) {
  __shared__ bf16 hs[64][136];   // 272B rows: 16B-aligned, even bank spread
  const int lane = threadIdx.x & 63;
  const int wid  = threadIdx.x >> 6;
  const int quad = lane >> 4, lc = lane & 15;
  const int bmw = blockIdx.x * 64 + wid * 16;
  const int rowc = min(bmw + lc, N - 1);
  // ---- GEMM0 ----
  const bf16* ap = A + (size_t)rowc * 256 + quad * 8;
  const short8* bp = (const short8*)Wp0 + lane;
  floatx4 acc[8] = {};
  #pragma unroll
  for (int kt = 0; kt < 8; ++kt) {
    short8 af = *(const short8*)(ap + kt * 32);
    #pragma unroll
    for (int nt = 0; nt < 8; ++nt) {
      short8 bfr = bp[(kt * 8 + nt) * 64];
      acc[nt] = __builtin_amdgcn_mfma_f32_16x16x32_bf16(af, bfr, acc[nt], 0, 0, 0);
    }
  }
  float bif[8], bof[8];
  #pragma unroll
  for (int nt = 0; nt < 8; ++nt) {
    bif[nt] = bi[nt * 16 + lc];
    bof[nt] = bo[nt * 16 + lc];
  }
  #pragma unroll
  for (int r = 0; r < 4; ++r) {
    int gmc = min(bmw + quad * 4 + r, N - 1);
    float ci = cin[gmc], co = cou[gmc];
    unsigned hp[4];
    #pragma unroll
    for (int np = 0; np < 4; ++np) {
      int n0 = 2 * np, n1 = 2 * np + 1;
      const bf16* h0row = h0 + ((size_t)np * N + gmc) * 32;
      float v0 = acc[n0][r] + ci * bif[n0] + co * bof[n0]
               + __bfloat162float(h0row[lc]);
      float v1 = acc[n1][r] + ci * bif[n1] + co * bof[n1]
               + __bfloat162float(h0row[16 + lc]);
      bf162 p = __float22bfloat162_rn(make_float2(tanhf(v0), tanhf(v1)));
      hp[np] = *(unsigned*)&p;
    }
    // permuted store: physical col lc*8+nt holds logical col nt*16+lc -> one b128 write
    *(uint4*)(&hs[wid * 16 + quad * 4 + r][lc * 8]) = make_uint4(hp[0], hp[1], hp[2], hp[3]);
  }
  __syncthreads();
  // ---- GEMM1 (A from LDS; Wp1 packed with matching K permutation) ----
  const short8* bp1 = (const short8*)Wp1 + lane;
  floatx4 acc2[12] = {};
  #pragma unroll
  for (int kt = 0; kt < 4; ++kt) {
    short8 af = *(const short8*)(&hs[wid * 16 + lc][kt * 32 + quad * 8]);
    #pragma unroll
    for (int nt = 0; nt < 12; ++nt) {
      short8 bfr = bp1[(kt * 12 + nt) * 64];
      acc2[nt] = __builtin_amdgcn_mfma_f32_16x16x32_bf16(af, bfr, acc2[nt], 0, 0, 0);
    }
  }
  #pragma unroll
  for (int r = 0; r < 4; ++r) {
    int gm = bmw + quad * 4 + r;
    if (gm < N) {
      #pragma unroll
      for (int nt = 0; nt < 12; ++nt) {
        int col = nt * 16 + lc;
        bf16 v = __float2bfloat16(acc2[nt][r]);
        if (col < 128) t1g[(size_t)gm * 128 + col]        = v;
        else           t1r[(size_t)gm * 64 + (col - 128)] = v;
      }
    }
  }
}

// ---------------- layer-1 gather + epilogue -> h2 (bf16), emb (fp32) ----------------
// dir = lane>>5 (in/out concurrent), 4 substreams/dir, 8 lanes x 16B uint4 per 128B dir-row.
// Packed float2 accumulation. Cross-half shfl_xor(32) combines in/out; dir0 writes h2b, dir1 writes emb.
__global__ __launch_bounds__(256) void k_agg1(const bf16* __restrict__ t1g, const bf16* __restrict__ t1r,
                                              const int* __restrict__ offsI, const int2* __restrict__ eI,
                                              const int* __restrict__ offsO, const int2* __restrict__ eO,
                                              const float* __restrict__ bi, const float* __restrict__ bo,
                                              const float* __restrict__ resb,
                                              const float* __restrict__ cin, const float* __restrict__ cou,
                                              bf16* __restrict__ h2b, float* __restrict__ emb, int N) {
  int n = (blockIdx.x * blockDim.x + threadIdx.x) >> 6;
  int lane = threadIdx.x & 63;
  if (n >= N) return;
  const int dir = lane >> 5;
  const int sub = (lane >> 3) & 3;
  const int sl  = lane & 7;
  const int*   offs = dir ? offsO : offsI;
  const int2*  el   = dir ? eO : eI;
  const char* base = (const char*)t1g + dir * 128 + sl * 16;
  floatx2 A0 = {0.f, 0.f}, A1 = {0.f, 0.f}, A2 = {0.f, 0.f}, A3 = {0.f, 0.f};
  const int s0 = offs[n], s1 = offs[n + 1];
  int i = s0 + sub;
  for (; i + 12 < s1; i += 16) {
    int2 eA = el[i], eB = el[i + 4], eC = el[i + 8], eD = el[i + 12];
    uint4 vA = *(const uint4*)(base + ((size_t)(unsigned)eA.x << 8));
    uint4 vB = *(const uint4*)(base + ((size_t)(unsigned)eB.x << 8));
    uint4 vC = *(const uint4*)(base + ((size_t)(unsigned)eC.x << 8));
    uint4 vD = *(const uint4*)(base + ((size_t)(unsigned)eD.x << 8));
    float fA = __int_as_float(eA.y), fB = __int_as_float(eB.y);
    float fC = __int_as_float(eC.y), fD = __int_as_float(eD.y);
    floatx2 wA = {fA, fA}, wB = {fB, fB}, wC = {fC, fC}, wD = {fD, fD};
    A0 += wA * bf2_to_f2(vA.x) + wB * bf2_to_f2(vB.x) + wC * bf2_to_f2(vC.x) + wD * bf2_to_f2(vD.x);
    A1 += wA * bf2_to_f2(vA.y) + wB * bf2_to_f2(vB.y) + wC * bf2_to_f2(vC.y) + wD * bf2_to_f2(vD.y);
    A2 += wA * bf2_to_f2(vA.z) + wB * bf2_to_f2(vB.z) + wC * bf2_to_f2(vC.z) + wD * bf2_to_f2(vD.z);
    A3 += wA * bf2_to_f2(vA.w) + wB * bf2_to_f2(vB.w) + wC * bf2_to_f2(vC.w) + wD * bf2_to_f2(vD.w);
  }
  for (; i < s1; i += 4) {
    int2 e = el[i];
    uint4 v = *(const uint4*)(base + ((size_t)(unsigned)e.x << 8));
    float f = __int_as_float(e.y);
    floatx2 w2 = {f, f};
    A0 += w2 * bf2_to_f2(v.x);
    A1 += w2 * bf2_to_f2(v.y);
    A2 += w2 * bf2_to_f2(v.z);
    A3 += w2 * bf2_to_f2(v.w);
  }
  float a0 = A0.x, a1 = A0.y, a2 = A1.x, a3 = A1.y;
  float a4 = A2.x, a5 = A2.y, a6 = A3.x, a7 = A3.y;
  // reduce over 4 substreams within each 32-lane half
  a0 += __shfl_xor(a0, 8, 64);  a1 += __shfl_xor(a1, 8, 64);
  a2 += __shfl_xor(a2, 8, 64);  a3 += __shfl_xor(a3, 8, 64);
  a4 += __shfl_xor(a4, 8, 64);  a5 += __shfl_xor(a5, 8, 64);
  a6 += __shfl_xor(a6, 8, 64);  a7 += __shfl_xor(a7, 8, 64);
  a0 += __shfl_xor(a0, 16, 64); a1 += __shfl_xor(a1, 16, 64);
  a2 += __shfl_xor(a2, 16, 64); a3 += __shfl_xor(a3, 16, 64);
  a4 += __shfl_xor(a4, 16, 64); a5 += __shfl_xor(a5, 16, 64);
  a6 += __shfl_xor(a6, 16, 64); a7 += __shfl_xor(a7, 16, 64);
  // exchange halves: get the other direction's sums
  float b0 = __shfl_xor(a0, 32, 64), b1 = __shfl_xor(a1, 32, 64);
  float b2 = __shfl_xor(a2, 32, 64), b3 = __shfl_xor(a3, 32, 64);
  float b4 = __shfl_xor(a4, 32, 64), b5 = __shfl_xor(a5, 32, 64);
  float b6 = __shfl_xor(a6, 32, 64), b7 = __shfl_xor(a7, 32, 64);
  if (sub == 0) {
    const int c = sl * 8;
    float ci = cin[n], co = cou[n];
    float s_in[8]  = { dir ? b0 : a0, dir ? b1 : a1, dir ? b2 : a2, dir ? b3 : a3,
                       dir ? b4 : a4, dir ? b5 : a5, dir ? b6 : a6, dir ? b7 : a7 };
    float s_ou[8]  = { dir ? a0 : b0, dir ? a1 : b1, dir ? a2 : b2, dir ? a3 : b3,
                       dir ? a4 : b4, dir ? a5 : b5, dir ? a6 : b6, dir ? a7 : b7 };
    float4 bif0 = *(const float4*)(bi + c),   bif1 = *(const float4*)(bi + c + 4);
    float4 bof0 = *(const float4*)(bo + c),   bof1 = *(const float4*)(bo + c + 4);
    float4 rbf0 = *(const float4*)(resb + c), rbf1 = *(const float4*)(resb + c + 4);
    uint4 rvu = *(const uint4*)((const char*)t1r + (size_t)n * 128 + sl * 16);
    float4 rv0 = bf4_to_f4(make_uint2(rvu.x, rvu.y));
    float4 rv1 = bf4_to_f4(make_uint2(rvu.z, rvu.w));
    float bif[8] = { bif0.x, bif0.y, bif0.z, bif0.w, bif1.x, bif1.y, bif1.z, bif1.w };
    float bof[8] = { bof0.x, bof0.y, bof0.z, bof0.w, bof1.x, bof1.y, bof1.z, bof1.w };
    float rbf[8] = { rbf0.x, rbf0.y, rbf0.z, rbf0.w, rbf1.x, rbf1.y, rbf1.z, rbf1.w };
    float rvf[8] = { rv0.x, rv0.y, rv0.z, rv0.w, rv1.x, rv1.y, rv1.z, rv1.w };
    float v[8];
    float q = 0.f;
    #pragma unroll
    for (int k = 0; k < 8; ++k) {
      v[k] = tanhf(ci * (s_in[k] + bif[k]) + co * (s_ou[k] + bof[k]) + rvf[k] + rbf[k]);
      q += v[k] * v[k];
    }
    q += __shfl_xor(q, 1, 64);
    q += __shfl_xor(q, 2, 64);
    q += __shfl_xor(q, 4, 64);
    if (dir == 0) {
      uint2 plo = f4_to_bf4(make_float4(v[0], v[1], v[2], v[3]));
      uint2 phi = f4_to_bf4(make_float4(v[4], v[5], v[6], v[7]));
      *(uint4*)(h2b + (size_t)n * 64 + c) = make_uint4(plo.x, plo.y, phi.x, phi.y);
    } else {
      float inv = 1.0f / (sqrtf(q) + 1e-12f);
      *(float4*)(emb + (size_t)n * 64 + c)     = make_float4(v[0] * inv, v[1] * inv, v[2] * inv, v[3] * inv);
      *(float4*)(emb + (size_t)n * 64 + c + 4) = make_float4(v[4] * inv, v[5] * inv, v[6] * inv, v[7] * inv);
    }
  }
}

// ---------------- decoder MFMA GEMM + log_softmax ----------------
__global__ __launch_bounds__(256) void k_mfd(const bf16* __restrict__ A,
                                             const bf16* __restrict__ Wp,
                                             const float* __restrict__ bd,
                                             float* __restrict__ logp, int N) {
  const int lane = threadIdx.x & 63;
  const int quad = lane >> 4, lc = lane & 15;
  const int bmw = blockIdx.x * 64 + (threadIdx.x >> 6) * 16;
  const int rowc = min(bmw + lc, N - 1);
  const bf16* ap = A + (size_t)rowc * 64 + quad * 8;
  const short8* bp = (const short8*)Wp + lane;
  floatx4 acc[8] = {};
  #pragma unroll
  for (int kt = 0; kt < 2; ++kt) {
    short8 af = *(const short8*)(ap + kt * 32);
    #pragma unroll
    for (int nt = 0; nt < 8; ++nt) {
      short8 bfr = bp[(kt * 8 + nt) * 64];
      acc[nt] = __builtin_amdgcn_mfma_f32_16x16x32_bf16(af, bfr, acc[nt], 0, 0, 0);
    }
  }
  float bdv[8];
  #pragma unroll
  for (int nt = 0; nt < 8; ++nt) bdv[nt] = bd[nt * 16 + lc];
  #pragma unroll
  for (int r = 0; r < 4; ++r) {
    int gm = bmw + quad * 4 + r;
    float v[8];
    #pragma unroll
    for (int nt = 0; nt < 8; ++nt) v[nt] = acc[nt][r] + bdv[nt];
    float m = v[0];
    #pragma unroll
    for (int nt = 1; nt < 8; ++nt) m = fmaxf(m, v[nt]);
    #pragma unroll
    for (int d = 1; d < 16; d <<= 1) m = fmaxf(m, __shfl_xor(m, d, 64));
    float s = 0.f;
    #pragma unroll
    for (int nt = 0; nt < 8; ++nt) s += __expf(v[nt] - m);
    #pragma unroll
    for (int d = 1; d < 16; d <<= 1) s += __shfl_xor(s, d, 64);
    float lse = m + __logf(s);
    if (gm < N) {
      #pragma unroll
      for (int nt = 0; nt < 8; ++nt) logp[(size_t)gm * 128 + nt * 16 + lc] = v[nt] - lse;
    }
  }
}

extern "C" void kernel_launch(void* const* d_in, const int* in_sizes, int n_in,
                              void* d_out, int out_size, void* d_ws, size_t ws_size,
                              hipStream_t stream) {
  const float* x     = (const float*)d_in[0];
  const int*   ei_in = (const int*)d_in[1];
  const float* ew_in = (const float*)d_in[2];
  const int*   ei_ou = (const int*)d_in[3];
  const float* ew_ou = (const float*)d_in[4];
  const float* pe    = (const float*)d_in[5];
  const float* Wmi0  = (const float*)d_in[6];
  const float* Wmo0  = (const float*)d_in[7];
  const float* Wsh0  = (const float*)d_in[8];
  const float* bmi0  = (const float*)d_in[9];
  const float* bmo0  = (const float*)d_in[10];
  const float* bsi0  = (const float*)d_in[11];
  const float* bso0  = (const float*)d_in[12];
  const float* cin0  = (const float*)d_in[13];
  const float* cou0  = (const float*)d_in[14];
  const float* Wmi1  = (const float*)d_in[15];
  const float* Wmo1  = (const float*)d_in[16];
  const float* Wsh1  = (const float*)d_in[17];
  const float* bmi1  = (const float*)d_in[18];
  const float* bmo1  = (const float*)d_in[19];
  const float* bsi1  = (const float*)d_in[20];
  const float* bso1  = (const float*)d_in[21];
  const float* cin1  = (const float*)d_in[22];
  const float* cou1  = (const float*)d_in[23];
  const float* resW  = (const float*)d_in[24];
  const float* resb  = (const float*)d_in[25];
  const float* Wd    = (const float*)d_in[26];
  const float* bd    = (const float*)d_in[27];

  const int N = in_sizes[0] / 128;
  const int E = in_sizes[2];
  const int NB = (N + BSZ - 1) >> 7;

  char* ws = (char*)d_ws;
  size_t off = 0;
  auto alloc = [&](size_t bytes) -> char* {
    off = (off + 255) & ~(size_t)255;
    char* p = ws + off;
    off += bytes;
    return p;
  };
  bf16*  h0bf  = (bf16*)alloc((size_t)N * 128 * 2);
  bf16*  aggC  = (bf16*)alloc((size_t)N * 256 * 2);   // later overlaid by t1g/t1r
  bf16*  h2b   = (bf16*)alloc((size_t)N * 64 * 2);
  bf16*  Wp0   = (bf16*)alloc(256 * 128 * 2);
  bf16*  Wp1   = (bf16*)alloc(128 * 192 * 2);
  bf16*  Wpd   = (bf16*)alloc(64 * 128 * 2);
  float* bi0   = (float*)alloc(128 * 4);
  float* bo0   = (float*)alloc(128 * 4);
  float* bi1   = (float*)alloc(64 * 4);
  float* bo1   = (float*)alloc(64 * 4);
  int*   bcnt  = (int*)alloc((size_t)2 * NBMAX * 4);
  int*   BO    = (int*)alloc((size_t)2 * NBMAX * 4);
  int*   bcur  = (int*)alloc((size_t)2 * NBMAX * 4);
  int*   offsI = (int*)alloc((size_t)(N + 1) * 4);
  int*   offsO = (int*)alloc((size_t)(N + 1) * 4);
  int2*  sI    = (int2*)alloc((size_t)E * 8);
  int2*  sO    = (int2*)alloc((size_t)E * 8);
  int2*  eI    = (int2*)alloc((size_t)E * 8);
  int2*  eO    = (int2*)alloc((size_t)E * 8);
  bf16* t1g = aggC;                       // overlay: aggC dead after k_mf01's GEMM0
  bf16* t1r = t1g + (size_t)N * 128;

  (void)hipMemsetAsync(bcnt, 0, (size_t)2 * NBMAX * 4, stream);

  dim3 gc((E + PACHUNK - 1) / PACHUNK, 2);
  k_bhist<<<gc, 256, 0, stream>>>(ei_in, ei_ou, E, bcnt, NB);
  k_bscan<<<2, 64, 0, stream>>>(bcnt, BO, bcur, NB);
  k_partA<<<gc, 256, 0, stream>>>(ei_in, ew_in, ei_ou, ew_ou, E, bcur, sI, sO, NB);
  dim3 gb(NB, 2);
  k_partB<<<gb, 256, 0, stream>>>(BO, bcur, sI, sO, eI, eO, offsI, offsO, N);
  k_packall<<<(8 * 8 * 64 + 4 * 12 * 64 + 2 * 8 * 64 + 128 + 255) / 256, 256, 0, stream>>>(
      Wmi0, Wmo0, Wsh0, Wmi1, Wmo1, Wsh1, resW, Wd,
      bmi0, bsi0, bmo0, bso0, bmi1, bsi1, bmo1, bso1,
      Wp0, Wp1, Wpd, bi0, bo0, bi1, bo1);
  k_prep0<<<(N * 128 + 255) / 256, 256, 0, stream>>>(x, pe, h0bf, N);

  int ab = (N + 3) / 4;
  int mb = (N + 63) / 64;
  // sliced agg0: grid = 8 * ceil(nwork/2), nwork = ceil(N/4); each block = 4 node-waves of one slice
  int nwork = (N + 3) / 4;
  int gj = (nwork + 1) / 2;
  k_agg0<<<gj * 8, 256, 0, stream>>>(h0bf, offsI, eI, offsO, eO, cin0, cou0, aggC, N);
  k_mf01<<<mb, 256, 0, stream>>>(aggC, Wp0, Wp1, bi0, bo0, cin0, cou0, h0bf, t1g, t1r, N);

  float* logp = (float*)d_out;
  float* emb  = logp + (size_t)N * 128;
  k_agg1<<<ab, 256, 0, stream>>>(t1g, t1r, offsI, eI, offsO, eO, bi1, bo1, resb, cin1, cou1,
                                 h2b, emb, N);
  k_mfd<<<mb, 256, 0, stream>>>(h2b, Wpd, bd, logp, N);
}

// Round 9
// 335.970 us; speedup vs baseline: 1.1658x; 1.1658x over previous
//
#include <hip/hip_runtime.h>
#include <hip/hip_bf16.h>
#include <math.h>

typedef __hip_bfloat16  bf16;
typedef __hip_bfloat162 bf162;
typedef __attribute__((ext_vector_type(8))) short short8;   // 8 bf16 = 4 VGPRs
typedef __attribute__((ext_vector_type(4))) float floatx4;  // MFMA acc
typedef __attribute__((ext_vector_type(2))) float floatx2;  // packed f32 (v_pk_fma_f32)

#define BSZ     128
#define NBMAX   512
#define PACHUNK 4096   // 36KB LDS in partA -> 4 blocks/CU

__device__ inline float4 bf4_to_f4(uint2 v) {
  float2 lo = __bfloat1622float2(*(bf162*)&v.x);
  float2 hi = __bfloat1622float2(*(bf162*)&v.y);
  return make_float4(lo.x, lo.y, hi.x, hi.y);
}
__device__ inline uint2 f4_to_bf4(float4 v) {
  bf162 lo = __float22bfloat162_rn(make_float2(v.x, v.y));
  bf162 hi = __float22bfloat162_rn(make_float2(v.z, v.w));
  uint2 r;
  r.x = *(unsigned*)&lo;
  r.y = *(unsigned*)&hi;
  return r;
}
// one bf162 word -> packed float2 {lo, hi}
__device__ inline floatx2 bf2_to_f2(unsigned u) {
  floatx2 r;
  r.x = __uint_as_float(u << 16);
  r.y = __uint_as_float(u & 0xffff0000u);
  return r;
}

// ---------------- bucket histogram: LDS-privatized, 1 global atomic per bucket per block ----------------
__global__ __launch_bounds__(256) void k_bhist(const int* __restrict__ eiIn, const int* __restrict__ eiOut,
                                               int E, int* __restrict__ bcnt, int NB) {
  __shared__ int h[NBMAX];
  const int t = threadIdx.x;
  const int set = blockIdx.y;
  const int* dst = (set ? eiOut : eiIn) + E;
  for (int i = t; i < NB; i += 256) h[i] = 0;
  __syncthreads();
  const int base = blockIdx.x * PACHUNK;
  const int m = min(PACHUNK, E - base);
  #pragma unroll 4
  for (int r = 0; r < PACHUNK / 256; ++r) {
    int i = r * 256 + t;
    if (i < m) atomicAdd(&h[dst[base + i] >> 7], 1);
  }
  __syncthreads();
  for (int i = t; i < NB; i += 256) {
    int c = h[i];
    if (c) atomicAdd(&bcnt[set * NBMAX + i], c);
  }
}

// ---------------- bucket scan: exclusive prefix over NB buckets -> BO, bcur ----------------
__global__ __launch_bounds__(64) void k_bscan(const int* __restrict__ bcnt,
                                              int* __restrict__ BO, int* __restrict__ bcur, int NB) {
  const int set = blockIdx.x;
  const int t = threadIdx.x;
  int carry = 0;
  for (int base = 0; base < NB; base += 64) {
    int idx = base + t;
    int v = (idx < NB) ? bcnt[set * NBMAX + idx] : 0;
    int incl = v;
    #pragma unroll
    for (int d = 1; d < 64; d <<= 1) {
      int u = __shfl_up(incl, d, 64);
      if (t >= d) incl += u;
    }
    if (idx < NB) {
      int e = carry + incl - v;
      BO[set * NBMAX + idx]   = e;
      bcur[set * NBMAX + idx] = e;
    }
    carry += __shfl(incl, 63, 64);
  }
}

// ---------------- partA: counting-sort edges into bucket-contiguous staging ----------------
__global__ __launch_bounds__(256) void k_partA(const int* __restrict__ eiIn, const float* __restrict__ ewIn,
                                               const int* __restrict__ eiOut, const float* __restrict__ ewOut,
                                               int E, int* __restrict__ bucketCur,
                                               int2* __restrict__ sI, int2* __restrict__ sO, int NB) {
  __shared__ int2 staged[PACHUNK];
  __shared__ int cnt[NBMAX];
  __shared__ int sb[NBMAX];
  const int t = threadIdx.x;
  const int set = blockIdx.y;
  const int*   ei = set ? eiOut : eiIn;
  const float* ew = set ? ewOut : ewIn;
  int2* stg  = set ? sO : sI;
  int*  bcur = bucketCur + set * NBMAX;
  const int base = blockIdx.x * PACHUNK;
  const int m = min(PACHUNK, E - base);
  for (int b = t; b < NB; b += 256) cnt[b] = 0;
  __syncthreads();
  #pragma unroll 4
  for (int r = 0; r < PACHUNK / 256; ++r) {
    int i = r * 256 + t;
    if (i < m) atomicAdd(&cnt[ei[E + base + i] >> 7], 1);
  }
  __syncthreads();
  if (t < 64) {
    int carry = 0;
    int nch = (NB + 63) >> 6;
    for (int c = 0; c < nch; ++c) {
      int idx = c * 64 + t;
      int v = (idx < NB) ? cnt[idx] : 0;
      int incl = v;
      #pragma unroll
      for (int d = 1; d < 64; d <<= 1) {
        int u = __shfl_up(incl, d, 64);
        if (t >= d) incl += u;
      }
      if (idx < NB) sb[idx] = carry + incl - v;
      carry += __shfl(incl, 63, 64);
    }
  }
  __syncthreads();
  for (int b = t; b < NB; b += 256) {
    int c = cnt[b];
    if (c > 0) cnt[b] = atomicAdd(&bcur[b], c) - sb[b];
  }
  __syncthreads();
  #pragma unroll 4
  for (int r = 0; r < PACHUNK / 256; ++r) {
    int i = r * 256 + t;
    if (i < m) {
      int src = ei[base + i];
      int dst = ei[E + base + i];
      float w = ew[base + i];
      int b = dst >> 7;
      int rank = atomicAdd(&sb[b], 1);
      staged[rank] = make_int2(src | ((dst & 127) << 16) | (b << 23), __float_as_int(w));
    }
  }
  __syncthreads();
  #pragma unroll 4
  for (int r = 0; r < PACHUNK / 256; ++r) {
    int j = r * 256 + t;
    if (j < m) {
      int2 p = staged[j];
      int b = ((unsigned)p.x) >> 23;
      stg[cnt[b] + j] = p;
    }
  }
}

// ---------------- partB: bucket staging -> per-node offsets (LDS scan) + final CSR order ----------------
__global__ __launch_bounds__(256) void k_partB(const int* __restrict__ BO, const int* __restrict__ bcur,
                                               const int2* __restrict__ sI, const int2* __restrict__ sO,
                                               int2* __restrict__ eI, int2* __restrict__ eO,
                                               int* __restrict__ offsI, int* __restrict__ offsO, int N) {
  __shared__ int cnt[BSZ];
  __shared__ int excl[BSZ];
  __shared__ int cur[BSZ];
  const int t = threadIdx.x;
  const int b = blockIdx.x;
  const int set = blockIdx.y;
  const int2* stg = set ? sO : sI;
  int2* out = set ? eO : eI;
  int*  offs = set ? offsO : offsI;
  const int nlo = b << 7;
  const int nodes = min(BSZ, N - nlo);
  const int lo = BO[set * NBMAX + b];
  const int hi = bcur[set * NBMAX + b];   // post-partA cursor == bucket end
  if (t < BSZ) cnt[t] = 0;
  __syncthreads();
  for (int i = lo + t; i < hi; i += 256) atomicAdd(&cnt[(stg[i].x >> 16) & 127], 1);
  __syncthreads();
  if (t < 64) {
    int v0 = cnt[t];
    int i0 = v0;
    #pragma unroll
    for (int d = 1; d < 64; d <<= 1) { int u = __shfl_up(i0, d, 64); if (t >= d) i0 += u; }
    int v1 = cnt[64 + t];
    int i1 = v1;
    #pragma unroll
    for (int d = 1; d < 64; d <<= 1) { int u = __shfl_up(i1, d, 64); if (t >= d) i1 += u; }
    int tot0 = __shfl(i0, 63, 64);
    excl[t]      = i0 - v0;
    excl[64 + t] = tot0 + i1 - v1;
  }
  __syncthreads();
  if (t < BSZ) cur[t] = lo + excl[t];
  if (t < nodes) offs[nlo + t] = lo + excl[t];
  if (b == gridDim.x - 1 && t == 0) offs[N] = hi;
  __syncthreads();
  for (int i = lo + t; i < hi; i += 256) {
    int2 p = stg[i];
    int dl = (p.x >> 16) & 127;
    int pos = atomicAdd(&cur[dl], 1);
    out[pos] = make_int2(p.x & 0xffff, p.y);
  }
}

// ---------------- pack all weights (direct from inputs, summed inline) + bias prep ----------------
// P1's K dimension is PERMUTED to match the LDS layout the fused mf01 kernel writes:
// physical k position p holds logical k = (p&7)*16 + (p>>3).
__device__ inline void pack_one(const float* __restrict__ W, bf16* __restrict__ P,
                                int id, int NT, int DO) {
  int lane = id & 63;
  int tile = id >> 6;
  int nt = tile % NT, kt = tile / NT;
  int col  = nt * 16 + (lane & 15);
  int krow = kt * 32 + (lane >> 4) * 8;
  bf16* dst = P + (size_t)id * 8;
  #pragma unroll
  for (int j = 0; j < 8; ++j) dst[j] = __float2bfloat16(W[(size_t)(krow + j) * DO + col]);
}
__global__ void k_packall(const float* __restrict__ Wmi0, const float* __restrict__ Wmo0,
                          const float* __restrict__ Ws0,
                          const float* __restrict__ Wmi1, const float* __restrict__ Wmo1,
                          const float* __restrict__ Ws1,
                          const float* __restrict__ resW, const float* __restrict__ Wd,
                          const float* __restrict__ bmi0, const float* __restrict__ bsi0,
                          const float* __restrict__ bmo0, const float* __restrict__ bso0,
                          const float* __restrict__ bmi1, const float* __restrict__ bsi1,
                          const float* __restrict__ bmo1, const float* __restrict__ bso1,
                          bf16* __restrict__ P0, bf16* __restrict__ P1, bf16* __restrict__ Pd,
                          float* __restrict__ bi0, float* __restrict__ bo0,
                          float* __restrict__ bi1, float* __restrict__ bo1) {
  int id = blockIdx.x * blockDim.x + threadIdx.x;
  const int T0 = 8 * 8 * 64;    // 256x128 (stacked [Wmi0+Ws0 ; Wmo0+Ws0])
  const int T1 = 4 * 12 * 64;   // 128x192 ([Wmi1+Ws1 | Wmo1+Ws1 | resW]), K permuted
  const int Td = 2 * 8 * 64;    // 64x128
  if (id < T0) {
    int lane = id & 63, tile = id >> 6;
    int nt = tile % 8, kt = tile / 8;
    int col  = nt * 16 + (lane & 15);
    int krow = kt * 32 + (lane >> 4) * 8;
    bf16* dst = P0 + (size_t)id * 8;
    #pragma unroll
    for (int j = 0; j < 8; ++j) {
      int r = krow + j;
      float v = (r < 128 ? Wmi0[r * 128 + col] : Wmo0[(r - 128) * 128 + col])
              + Ws0[(r & 127) * 128 + col];
      dst[j] = __float2bfloat16(v);
    }
  } else if (id < T0 + T1) {
    int id1 = id - T0;
    int lane = id1 & 63, tile = id1 >> 6;
    int nt = tile % 12, kt = tile / 12;
    int col  = nt * 16 + (lane & 15);
    int krow = kt * 32 + (lane >> 4) * 8;
    bf16* dst = P1 + (size_t)id1 * 8;
    #pragma unroll
    for (int j = 0; j < 8; ++j) {
      int kp = krow + j;
      int k = ((kp & 7) << 4) + (kp >> 3);   // inverse of mf01's LDS column permutation
      float v;
      if (col < 64)       v = Wmi1[k * 64 + col]       + Ws1[k * 64 + col];
      else if (col < 128) v = Wmo1[k * 64 + col - 64]  + Ws1[k * 64 + col - 64];
      else                v = resW[k * 64 + col - 128];
      dst[j] = __float2bfloat16(v);
    }
  } else if (id < T0 + T1 + Td) {
    pack_one(Wd, Pd, id - T0 - T1, 8, 128);
  } else {
    int j = id - (T0 + T1 + Td);
    if (j < 128) { bi0[j] = bmi0[j] + bsi0[j]; bo0[j] = bmo0[j] + bso0[j]; }
    if (j < 64)  { bi1[j] = bmi1[j] + bsi1[j]; bo1[j] = bmo1[j] + bso1[j]; }
  }
}

// ---------------- h0 table: bf16(x + pe), row-major [N][128] ----------------
__global__ void k_prep0(const float* __restrict__ x, const float* __restrict__ pe,
                        bf16* __restrict__ h0, int total) {
  int i = blockIdx.x * blockDim.x + threadIdx.x;
  if (i < total) h0[i] = __float2bfloat16(x[i] + pe[i & 127]);
}

// ---------------- layer-0 gather: aggC = [ci*prop_in(h0) | co*prop_out(h0)] (bf16, N x 256) ----------------
// One node per wave. dir = lane>>5, 2 substreams/dir, 16 lanes x 16B uint4 per 256B row.
// 4-deep unroll (empirical optimum: r7's 8-deep and r8's slicing both regressed); pk-fma accumulation.
__global__ __launch_bounds__(256) void k_agg0(const bf16* __restrict__ tb,
                                              const int* __restrict__ offsI, const int2* __restrict__ eI,
                                              const int* __restrict__ offsO, const int2* __restrict__ eO,
                                              const float* __restrict__ cin, const float* __restrict__ cou,
                                              bf16* __restrict__ aggC, int N) {
  int n = (blockIdx.x * blockDim.x + threadIdx.x) >> 6;
  int lane = threadIdx.x & 63;
  if (n >= N) return;
  const int dir = lane >> 5;
  const int sub = (lane >> 4) & 1;
  const int sl  = lane & 15;
  const int*   offs = dir ? offsO : offsI;
  const int2*  el   = dir ? eO : eI;
  const float* cc   = dir ? cou : cin;
  const char* base = (const char*)tb + sl * 16;
  floatx2 A0 = {0.f, 0.f}, A1 = {0.f, 0.f}, A2 = {0.f, 0.f}, A3 = {0.f, 0.f};
  const int s0 = offs[n], s1 = offs[n + 1];
  int i = s0 + sub;
  for (; i + 6 < s1; i += 8) {
    int2 eA = el[i], eB = el[i + 2], eC = el[i + 4], eD = el[i + 6];
    uint4 vA = *(const uint4*)(base + ((size_t)(unsigned)eA.x << 8));
    uint4 vB = *(const uint4*)(base + ((size_t)(unsigned)eB.x << 8));
    uint4 vC = *(const uint4*)(base + ((size_t)(unsigned)eC.x << 8));
    uint4 vD = *(const uint4*)(base + ((size_t)(unsigned)eD.x << 8));
    float fA = __int_as_float(eA.y), fB = __int_as_float(eB.y);
    float fC = __int_as_float(eC.y), fD = __int_as_float(eD.y);
    floatx2 wA = {fA, fA}, wB = {fB, fB}, wC = {fC, fC}, wD = {fD, fD};
    A0 += wA * bf2_to_f2(vA.x) + wB * bf2_to_f2(vB.x) + wC * bf2_to_f2(vC.x) + wD * bf2_to_f2(vD.x);
    A1 += wA * bf2_to_f2(vA.y) + wB * bf2_to_f2(vB.y) + wC * bf2_to_f2(vC.y) + wD * bf2_to_f2(vD.y);
    A2 += wA * bf2_to_f2(vA.z) + wB * bf2_to_f2(vB.z) + wC * bf2_to_f2(vC.z) + wD * bf2_to_f2(vD.z);
    A3 += wA * bf2_to_f2(vA.w) + wB * bf2_to_f2(vB.w) + wC * bf2_to_f2(vC.w) + wD * bf2_to_f2(vD.w);
  }
  for (; i < s1; i += 2) {
    int2 e = el[i];
    uint4 v = *(const uint4*)(base + ((size_t)(unsigned)e.x << 8));
    float f = __int_as_float(e.y);
    floatx2 w2 = {f, f};
    A0 += w2 * bf2_to_f2(v.x);
    A1 += w2 * bf2_to_f2(v.y);
    A2 += w2 * bf2_to_f2(v.z);
    A3 += w2 * bf2_to_f2(v.w);
  }
  float a0 = A0.x, a1 = A0.y, a2 = A1.x, a3 = A1.y;
  float a4 = A2.x, a5 = A2.y, a6 = A3.x, a7 = A3.y;
  a0 += __shfl_xor(a0, 16, 64); a1 += __shfl_xor(a1, 16, 64);
  a2 += __shfl_xor(a2, 16, 64); a3 += __shfl_xor(a3, 16, 64);
  a4 += __shfl_xor(a4, 16, 64); a5 += __shfl_xor(a5, 16, 64);
  a6 += __shfl_xor(a6, 16, 64); a7 += __shfl_xor(a7, 16, 64);
  if (sub == 0) {
    float c = cc[n];
    uint2 plo = f4_to_bf4(make_float4(c * a0, c * a1, c * a2, c * a3));
    uint2 phi = f4_to_bf4(make_float4(c * a4, c * a5, c * a6, c * a7));
    *(uint4*)(aggC + (size_t)n * 256 + dir * 128 + sl * 8) = make_uint4(plo.x, plo.y, phi.x, phi.y);
  }
}

// ---------------- FUSED layer-0 GEMM + epilogue + layer-1 GEMM ----------------
// GEMM0: aggC(256)@Wp0 -> h1 = tanh(.. + h0), kept in LDS (column-permuted: [row][lc*8+nt]).
// GEMM1: h1(LDS)@Wp1(K-permuted) -> [t1g | t1r]. h1 never touches global memory.
__global__ __launch_bounds__(256) void k_mf01(const bf16* __restrict__ A,
                                              const bf16* __restrict__ Wp0,
                                              const bf16* __restrict__ Wp1,
                                              const float* __restrict__ bi, const float* __restrict__ bo,
                                              const float* __restrict__ cin, const float* __restrict__ cou,
                                              const bf16* __restrict__ h0,
                                              bf16* __restrict__ t1g, bf16* __restrict__ t1r, int N) {
  __shared__ bf16 hs[64][136];   // 272B rows: 16B-aligned, even bank spread
  const int lane = threadIdx.x & 63;
  const int wid  = threadIdx.x >> 6;
  const int quad = lane >> 4, lc = lane & 15;
  const int bmw = blockIdx.x * 64 + wid * 16;
  const int rowc = min(bmw + lc, N - 1);
  // ---- GEMM0 ----
  const bf16* ap = A + (size_t)rowc * 256 + quad * 8;
  const short8* bp = (const short8*)Wp0 + lane;
  floatx4 acc[8] = {};
  #pragma unroll
  for (int kt = 0; kt < 8; ++kt) {
    short8 af = *(const short8*)(ap + kt * 32);
    #pragma unroll
    for (int nt = 0; nt < 8; ++nt) {
      short8 bfr = bp[(kt * 8 + nt) * 64];
      acc[nt] = __builtin_amdgcn_mfma_f32_16x16x32_bf16(af, bfr, acc[nt], 0, 0, 0);
    }
  }
  float bif[8], bof[8];
  #pragma unroll
  for (int nt = 0; nt < 8; ++nt) {
    bif[nt] = bi[nt * 16 + lc];
    bof[nt] = bo[nt * 16 + lc];
  }
  #pragma unroll
  for (int r = 0; r < 4; ++r) {
    int gmc = min(bmw + quad * 4 + r, N - 1);
    float ci = cin[gmc], co = cou[gmc];
    unsigned hp[4];
    #pragma unroll
    for (int np = 0; np < 4; ++np) {
      int n0 = 2 * np, n1 = 2 * np + 1;
      float v0 = acc[n0][r] + ci * bif[n0] + co * bof[n0]
               + __bfloat162float(h0[(size_t)gmc * 128 + n0 * 16 + lc]);
      float v1 = acc[n1][r] + ci * bif[n1] + co * bof[n1]
               + __bfloat162float(h0[(size_t)gmc * 128 + n1 * 16 + lc]);
      bf162 p = __float22bfloat162_rn(make_float2(tanhf(v0), tanhf(v1)));
      hp[np] = *(unsigned*)&p;
    }
    // permuted store: physical col lc*8+nt holds logical col nt*16+lc -> one b128 write
    *(uint4*)(&hs[wid * 16 + quad * 4 + r][lc * 8]) = make_uint4(hp[0], hp[1], hp[2], hp[3]);
  }
  __syncthreads();
  // ---- GEMM1 (A from LDS; Wp1 packed with matching K permutation) ----
  const short8* bp1 = (const short8*)Wp1 + lane;
  floatx4 acc2[12] = {};
  #pragma unroll
  for (int kt = 0; kt < 4; ++kt) {
    short8 af = *(const short8*)(&hs[wid * 16 + lc][kt * 32 + quad * 8]);
    #pragma unroll
    for (int nt = 0; nt < 12; ++nt) {
      short8 bfr = bp1[(kt * 12 + nt) * 64];
      acc2[nt] = __builtin_amdgcn_mfma_f32_16x16x32_bf16(af, bfr, acc2[nt], 0, 0, 0);
    }
  }
  #pragma unroll
  for (int r = 0; r < 4; ++r) {
    int gm = bmw + quad * 4 + r;
    if (gm < N) {
      #pragma unroll
      for (int nt = 0; nt < 12; ++nt) {
        int col = nt * 16 + lc;
        bf16 v = __float2bfloat16(acc2[nt][r]);
        if (col < 128) t1g[(size_t)gm * 128 + col]        = v;
        else           t1r[(size_t)gm * 64 + (col - 128)] = v;
      }
    }
  }
}

// ---------------- layer-1 gather + epilogue -> h2 (bf16), emb (fp32) ----------------
// dir = lane>>5 (in/out concurrent), 4 substreams/dir, 8 lanes x 16B uint4 per 128B dir-row.
// Packed float2 accumulation. Cross-half shfl_xor(32) combines in/out; dir0 writes h2b, dir1 writes emb.
__global__ __launch_bounds__(256) void k_agg1(const bf16* __restrict__ t1g, const bf16* __restrict__ t1r,
                                              const int* __restrict__ offsI, const int2* __restrict__ eI,
                                              const int* __restrict__ offsO, const int2* __restrict__ eO,
                                              const float* __restrict__ bi, const float* __restrict__ bo,
                                              const float* __restrict__ resb,
                                              const float* __restrict__ cin, const float* __restrict__ cou,
                                              bf16* __restrict__ h2b, float* __restrict__ emb, int N) {
  int n = (blockIdx.x * blockDim.x + threadIdx.x) >> 6;
  int lane = threadIdx.x & 63;
  if (n >= N) return;
  const int dir = lane >> 5;
  const int sub = (lane >> 3) & 3;
  const int sl  = lane & 7;
  const int*   offs = dir ? offsO : offsI;
  const int2*  el   = dir ? eO : eI;
  const char* base = (const char*)t1g + dir * 128 + sl * 16;
  floatx2 A0 = {0.f, 0.f}, A1 = {0.f, 0.f}, A2 = {0.f, 0.f}, A3 = {0.f, 0.f};
  const int s0 = offs[n], s1 = offs[n + 1];
  int i = s0 + sub;
  for (; i + 12 < s1; i += 16) {
    int2 eA = el[i], eB = el[i + 4], eC = el[i + 8], eD = el[i + 12];
    uint4 vA = *(const uint4*)(base + ((size_t)(unsigned)eA.x << 8));
    uint4 vB = *(const uint4*)(base + ((size_t)(unsigned)eB.x << 8));
    uint4 vC = *(const uint4*)(base + ((size_t)(unsigned)eC.x << 8));
    uint4 vD = *(const uint4*)(base + ((size_t)(unsigned)eD.x << 8));
    float fA = __int_as_float(eA.y), fB = __int_as_float(eB.y);
    float fC = __int_as_float(eC.y), fD = __int_as_float(eD.y);
    floatx2 wA = {fA, fA}, wB = {fB, fB}, wC = {fC, fC}, wD = {fD, fD};
    A0 += wA * bf2_to_f2(vA.x) + wB * bf2_to_f2(vB.x) + wC * bf2_to_f2(vC.x) + wD * bf2_to_f2(vD.x);
    A1 += wA * bf2_to_f2(vA.y) + wB * bf2_to_f2(vB.y) + wC * bf2_to_f2(vC.y) + wD * bf2_to_f2(vD.y);
    A2 += wA * bf2_to_f2(vA.z) + wB * bf2_to_f2(vB.z) + wC * bf2_to_f2(vC.z) + wD * bf2_to_f2(vD.z);
    A3 += wA * bf2_to_f2(vA.w) + wB * bf2_to_f2(vB.w) + wC * bf2_to_f2(vC.w) + wD * bf2_to_f2(vD.w);
  }
  for (; i < s1; i += 4) {
    int2 e = el[i];
    uint4 v = *(const uint4*)(base + ((size_t)(unsigned)e.x << 8));
    float f = __int_as_float(e.y);
    floatx2 w2 = {f, f};
    A0 += w2 * bf2_to_f2(v.x);
    A1 += w2 * bf2_to_f2(v.y);
    A2 += w2 * bf2_to_f2(v.z);
    A3 += w2 * bf2_to_f2(v.w);
  }
  float a0 = A0.x, a1 = A0.y, a2 = A1.x, a3 = A1.y;
  float a4 = A2.x, a5 = A2.y, a6 = A3.x, a7 = A3.y;
  // reduce over 4 substreams within each 32-lane half
  a0 += __shfl_xor(a0, 8, 64);  a1 += __shfl_xor(a1, 8, 64);
  a2 += __shfl_xor(a2, 8, 64);  a3 += __shfl_xor(a3, 8, 64);
  a4 += __shfl_xor(a4, 8, 64);  a5 += __shfl_xor(a5, 8, 64);
  a6 += __shfl_xor(a6, 8, 64);  a7 += __shfl_xor(a7, 8, 64);
  a0 += __shfl_xor(a0, 16, 64); a1 += __shfl_xor(a1, 16, 64);
  a2 += __shfl_xor(a2, 16, 64); a3 += __shfl_xor(a3, 16, 64);
  a4 += __shfl_xor(a4, 16, 64); a5 += __shfl_xor(a5, 16, 64);
  a6 += __shfl_xor(a6, 16, 64); a7 += __shfl_xor(a7, 16, 64);
  // exchange halves: get the other direction's sums
  float b0 = __shfl_xor(a0, 32, 64), b1 = __shfl_xor(a1, 32, 64);
  float b2 = __shfl_xor(a2, 32, 64), b3 = __shfl_xor(a3, 32, 64);
  float b4 = __shfl_xor(a4, 32, 64), b5 = __shfl_xor(a5, 32, 64);
  float b6 = __shfl_xor(a6, 32, 64), b7 = __shfl_xor(a7, 32, 64);
  if (sub == 0) {
    const int c = sl * 8;
    float ci = cin[n], co = cou[n];
    float s_in[8]  = { dir ? b0 : a0, dir ? b1 : a1, dir ? b2 : a2, dir ? b3 : a3,
                       dir ? b4 : a4, dir ? b5 : a5, dir ? b6 : a6, dir ? b7 : a7 };
    float s_ou[8]  = { dir ? a0 : b0, dir ? a1 : b1, dir ? a2 : b2, dir ? a3 : b3,
                       dir ? a4 : b4, dir ? a5 : b5, dir ? a6 : b6, dir ? a7 : b7 };
    float4 bif0 = *(const float4*)(bi + c),   bif1 = *(const float4*)(bi + c + 4);
    float4 bof0 = *(const float4*)(bo + c),   bof1 = *(const float4*)(bo + c + 4);
    float4 rbf0 = *(const float4*)(resb + c), rbf1 = *(const float4*)(resb + c + 4);
    uint4 rvu = *(const uint4*)((const char*)t1r + (size_t)n * 128 + sl * 16);
    float4 rv0 = bf4_to_f4(make_uint2(rvu.x, rvu.y));
    float4 rv1 = bf4_to_f4(make_uint2(rvu.z, rvu.w));
    float bif[8] = { bif0.x, bif0.y, bif0.z, bif0.w, bif1.x, bif1.y, bif1.z, bif1.w };
    float bof[8] = { bof0.x, bof0.y, bof0.z, bof0.w, bof1.x, bof1.y, bof1.z, bof1.w };
    float rbf[8] = { rbf0.x, rbf0.y, rbf0.z, rbf0.w, rbf1.x, rbf1.y, rbf1.z, rbf1.w };
    float rvf[8] = { rv0.x, rv0.y, rv0.z, rv0.w, rv1.x, rv1.y, rv1.z, rv1.w };
    float v[8];
    float q = 0.f;
    #pragma unroll
    for (int k = 0; k < 8; ++k) {
      v[k] = tanhf(ci * (s_in[k] + bif[k]) + co * (s_ou[k] + bof[k]) + rvf[k] + rbf[k]);
      q += v[k] * v[k];
    }
    q += __shfl_xor(q, 1, 64);
    q += __shfl_xor(q, 2, 64);
    q += __shfl_xor(q, 4, 64);
    if (dir == 0) {
      uint2 plo = f4_to_bf4(make_float4(v[0], v[1], v[2], v[3]));
      uint2 phi = f4_to_bf4(make_float4(v[4], v[5], v[6], v[7]));
      *(uint4*)(h2b + (size_t)n * 64 + c) = make_uint4(plo.x, plo.y, phi.x, phi.y);
    } else {
      float inv = 1.0f / (sqrtf(q) + 1e-12f);
      *(float4*)(emb + (size_t)n * 64 + c)     = make_float4(v[0] * inv, v[1] * inv, v[2] * inv, v[3] * inv);
      *(float4*)(emb + (size_t)n * 64 + c + 4) = make_float4(v[4] * inv, v[5] * inv, v[6] * inv, v[7] * inv);
    }
  }
}

// ---------------- decoder MFMA GEMM + log_softmax ----------------
__global__ __launch_bounds__(256) void k_mfd(const bf16* __restrict__ A,
                                             const bf16* __restrict__ Wp,
                                             const float* __restrict__ bd,
                                             float* __restrict__ logp, int N) {
  const int lane = threadIdx.x & 63;
  const int quad = lane >> 4, lc = lane & 15;
  const int bmw = blockIdx.x * 64 + (threadIdx.x >> 6) * 16;
  const int rowc = min(bmw + lc, N - 1);
  const bf16* ap = A + (size_t)rowc * 64 + quad * 8;
  const short8* bp = (const short8*)Wp + lane;
  floatx4 acc[8] = {};
  #pragma unroll
  for (int kt = 0; kt < 2; ++kt) {
    short8 af = *(const short8*)(ap + kt * 32);
    #pragma unroll
    for (int nt = 0; nt < 8; ++nt) {
      short8 bfr = bp[(kt * 8 + nt) * 64];
      acc[nt] = __builtin_amdgcn_mfma_f32_16x16x32_bf16(af, bfr, acc[nt], 0, 0, 0);
    }
  }
  float bdv[8];
  #pragma unroll
  for (int nt = 0; nt < 8; ++nt) bdv[nt] = bd[nt * 16 + lc];
  #pragma unroll
  for (int r = 0; r < 4; ++r) {
    int gm = bmw + quad * 4 + r;
    float v[8];
    #pragma unroll
    for (int nt = 0; nt < 8; ++nt) v[nt] = acc[nt][r] + bdv[nt];
    float m = v[0];
    #pragma unroll
    for (int nt = 1; nt < 8; ++nt) m = fmaxf(m, v[nt]);
    #pragma unroll
    for (int d = 1; d < 16; d <<= 1) m = fmaxf(m, __shfl_xor(m, d, 64));
    float s = 0.f;
    #pragma unroll
    for (int nt = 0; nt < 8; ++nt) s += __expf(v[nt] - m);
    #pragma unroll
    for (int d = 1; d < 16; d <<= 1) s += __shfl_xor(s, d, 64);
    float lse = m + __logf(s);
    if (gm < N) {
      #pragma unroll
      for (int nt = 0; nt < 8; ++nt) logp[(size_t)gm * 128 + nt * 16 + lc] = v[nt] - lse;
    }
  }
}

extern "C" void kernel_launch(void* const* d_in, const int* in_sizes, int n_in,
                              void* d_out, int out_size, void* d_ws, size_t ws_size,
                              hipStream_t stream) {
  const float* x     = (const float*)d_in[0];
  const int*   ei_in = (const int*)d_in[1];
  const float* ew_in = (const float*)d_in[2];
  const int*   ei_ou = (const int*)d_in[3];
  const float* ew_ou = (const float*)d_in[4];
  const float* pe    = (const float*)d_in[5];
  const float* Wmi0  = (const float*)d_in[6];
  const float* Wmo0  = (const float*)d_in[7];
  const float* Wsh0  = (const float*)d_in[8];
  const float* bmi0  = (const float*)d_in[9];
  const float* bmo0  = (const float*)d_in[10];
  const float* bsi0  = (const float*)d_in[11];
  const float* bso0  = (const float*)d_in[12];
  const float* cin0  = (const float*)d_in[13];
  const float* cou0  = (const float*)d_in[14];
  const float* Wmi1  = (const float*)d_in[15];
  const float* Wmo1  = (const float*)d_in[16];
  const float* Wsh1  = (const float*)d_in[17];
  const float* bmi1  = (const float*)d_in[18];
  const float* bmo1  = (const float*)d_in[19];
  const float* bsi1  = (const float*)d_in[20];
  const float* bso1  = (const float*)d_in[21];
  const float* cin1  = (const float*)d_in[22];
  const float* cou1  = (const float*)d_in[23];
  const float* resW  = (const float*)d_in[24];
  const float* resb  = (const float*)d_in[25];
  const float* Wd    = (const float*)d_in[26];
  const float* bd    = (const float*)d_in[27];

  const int N = in_sizes[0] / 128;
  const int E = in_sizes[2];
  const int NB = (N + BSZ - 1) >> 7;

  char* ws = (char*)d_ws;
  size_t off = 0;
  auto alloc = [&](size_t bytes) -> char* {
    off = (off + 255) & ~(size_t)255;
    char* p = ws + off;
    off += bytes;
    return p;
  };
  bf16*  h0bf  = (bf16*)alloc((size_t)N * 128 * 2);
  bf16*  aggC  = (bf16*)alloc((size_t)N * 256 * 2);   // later overlaid by t1g/t1r
  bf16*  h2b   = (bf16*)alloc((size_t)N * 64 * 2);
  bf16*  Wp0   = (bf16*)alloc(256 * 128 * 2);
  bf16*  Wp1   = (bf16*)alloc(128 * 192 * 2);
  bf16*  Wpd   = (bf16*)alloc(64 * 128 * 2);
  float* bi0   = (float*)alloc(128 * 4);
  float* bo0   = (float*)alloc(128 * 4);
  float* bi1   = (float*)alloc(64 * 4);
  float* bo1   = (float*)alloc(64 * 4);
  int*   bcnt  = (int*)alloc((size_t)2 * NBMAX * 4);
  int*   BO    = (int*)alloc((size_t)2 * NBMAX * 4);
  int*   bcur  = (int*)alloc((size_t)2 * NBMAX * 4);
  int*   offsI = (int*)alloc((size_t)(N + 1) * 4);
  int*   offsO = (int*)alloc((size_t)(N + 1) * 4);
  int2*  sI    = (int2*)alloc((size_t)E * 8);
  int2*  sO    = (int2*)alloc((size_t)E * 8);
  int2*  eI    = (int2*)alloc((size_t)E * 8);
  int2*  eO    = (int2*)alloc((size_t)E * 8);
  bf16* t1g = aggC;                       // overlay: aggC dead after k_mf01's GEMM0
  bf16* t1r = t1g + (size_t)N * 128;

  (void)hipMemsetAsync(bcnt, 0, (size_t)2 * NBMAX * 4, stream);

  dim3 gc((E + PACHUNK - 1) / PACHUNK, 2);
  k_bhist<<<gc, 256, 0, stream>>>(ei_in, ei_ou, E, bcnt, NB);
  k_bscan<<<2, 64, 0, stream>>>(bcnt, BO, bcur, NB);
  k_partA<<<gc, 256, 0, stream>>>(ei_in, ew_in, ei_ou, ew_ou, E, bcur, sI, sO, NB);
  dim3 gb(NB, 2);
  k_partB<<<gb, 256, 0, stream>>>(BO, bcur, sI, sO, eI, eO, offsI, offsO, N);
  k_packall<<<(8 * 8 * 64 + 4 * 12 * 64 + 2 * 8 * 64 + 128 + 255) / 256, 256, 0, stream>>>(
      Wmi0, Wmo0, Wsh0, Wmi1, Wmo1, Wsh1, resW, Wd,
      bmi0, bsi0, bmo0, bso0, bmi1, bsi1, bmo1, bso1,
      Wp0, Wp1, Wpd, bi0, bo0, bi1, bo1);
  k_prep0<<<(N * 128 + 255) / 256, 256, 0, stream>>>(x, pe, h0bf, N * 128);

  int ab = (N + 3) / 4;
  int mb = (N + 63) / 64;
  k_agg0<<<ab, 256, 0, stream>>>(h0bf, offsI, eI, offsO, eO, cin0, cou0, aggC, N);
  k_mf01<<<mb, 256, 0, stream>>>(aggC, Wp0, Wp1, bi0, bo0, cin0, cou0, h0bf, t1g, t1r, N);

  float* logp = (float*)d_out;
  float* emb  = logp + (size_t)N * 128;
  k_agg1<<<ab, 256, 0, stream>>>(t1g, t1r, offsI, eI, offsO, eO, bi1, bo1, resb, cin1, cou1,
                                 h2b, emb, N);
  k_mfd<<<mb, 256, 0, stream>>>(h2b, Wpd, bd, logp, N);
}

// Round 10
// 333.805 us; speedup vs baseline: 1.1733x; 1.0065x over previous
//
#include <hip/hip_runtime.h>
#include <hip/hip_bf16.h>
#include <math.h>

typedef __hip_bfloat16  bf16;
typedef __hip_bfloat162 bf162;
typedef __attribute__((ext_vector_type(8))) short short8;   // 8 bf16 = 4 VGPRs
typedef __attribute__((ext_vector_type(4))) float floatx4;  // MFMA acc
typedef __attribute__((ext_vector_type(2))) float floatx2;  // packed f32 (v_pk_fma_f32)

#define BSZ     128
#define NBMAX   512
#define PACHUNK 4096   // 36KB LDS in partA -> 4 blocks/CU
#define PBCAP   4608   // partB LDS staging cap (bucket avg ~2048, 5-sigma ~2300)

__device__ inline float4 bf4_to_f4(uint2 v) {
  float2 lo = __bfloat1622float2(*(bf162*)&v.x);
  float2 hi = __bfloat1622float2(*(bf162*)&v.y);
  return make_float4(lo.x, lo.y, hi.x, hi.y);
}
__device__ inline uint2 f4_to_bf4(float4 v) {
  bf162 lo = __float22bfloat162_rn(make_float2(v.x, v.y));
  bf162 hi = __float22bfloat162_rn(make_float2(v.z, v.w));
  uint2 r;
  r.x = *(unsigned*)&lo;
  r.y = *(unsigned*)&hi;
  return r;
}
// one bf162 word -> packed float2 {lo, hi}
__device__ inline floatx2 bf2_to_f2(unsigned u) {
  floatx2 r;
  r.x = __uint_as_float(u << 16);
  r.y = __uint_as_float(u & 0xffff0000u);
  return r;
}

// ---------------- bucket histogram: LDS-privatized; persists per-chunk histogram for partA ----------------
__global__ __launch_bounds__(256) void k_bhist(const int* __restrict__ eiIn, const int* __restrict__ eiOut,
                                               int E, int* __restrict__ bcnt, int* __restrict__ bh, int NB) {
  __shared__ int h[NBMAX];
  const int t = threadIdx.x;
  const int set = blockIdx.y;
  const int* dst = (set ? eiOut : eiIn) + E;
  for (int i = t; i < NB; i += 256) h[i] = 0;
  __syncthreads();
  const int base = blockIdx.x * PACHUNK;
  const int m = min(PACHUNK, E - base);
  if (m == PACHUNK && (E & 3) == 0) {
    const int4* d4 = (const int4*)(dst + base);
    #pragma unroll
    for (int r = 0; r < PACHUNK / 1024; ++r) {
      int4 v = d4[r * 256 + t];
      atomicAdd(&h[v.x >> 7], 1);
      atomicAdd(&h[v.y >> 7], 1);
      atomicAdd(&h[v.z >> 7], 1);
      atomicAdd(&h[v.w >> 7], 1);
    }
  } else {
    for (int r = 0; r < PACHUNK / 256; ++r) {
      int i = r * 256 + t;
      if (i < m) atomicAdd(&h[dst[base + i] >> 7], 1);
    }
  }
  __syncthreads();
  int* bhrow = bh + ((size_t)set * gridDim.x + blockIdx.x) * NBMAX;
  for (int i = t; i < NB; i += 256) {
    int c = h[i];
    bhrow[i] = c;
    if (c) atomicAdd(&bcnt[set * NBMAX + i], c);
  }
}

// ---------------- bucket scan: exclusive prefix over NB buckets -> BO, bcur ----------------
__global__ __launch_bounds__(64) void k_bscan(const int* __restrict__ bcnt,
                                              int* __restrict__ BO, int* __restrict__ bcur, int NB) {
  const int set = blockIdx.x;
  const int t = threadIdx.x;
  int carry = 0;
  for (int base = 0; base < NB; base += 64) {
    int idx = base + t;
    int v = (idx < NB) ? bcnt[set * NBMAX + idx] : 0;
    int incl = v;
    #pragma unroll
    for (int d = 1; d < 64; d <<= 1) {
      int u = __shfl_up(incl, d, 64);
      if (t >= d) incl += u;
    }
    if (idx < NB) {
      int e = carry + incl - v;
      BO[set * NBMAX + idx]   = e;
      bcur[set * NBMAX + idx] = e;
    }
    carry += __shfl(incl, 63, 64);
  }
}

// ---------------- partA: counting-sort edges into bucket-contiguous staging ----------------
// Histogram pass ELIMINATED: loads this chunk's counts from bh (written by k_bhist).
__global__ __launch_bounds__(256) void k_partA(const int* __restrict__ eiIn, const float* __restrict__ ewIn,
                                               const int* __restrict__ eiOut, const float* __restrict__ ewOut,
                                               int E, int* __restrict__ bucketCur, const int* __restrict__ bh,
                                               int2* __restrict__ sI, int2* __restrict__ sO, int NB) {
  __shared__ int2 staged[PACHUNK];
  __shared__ int cnt[NBMAX];
  __shared__ int sb[NBMAX];
  const int t = threadIdx.x;
  const int set = blockIdx.y;
  const int*   ei = set ? eiOut : eiIn;
  const float* ew = set ? ewOut : ewIn;
  int2* stg  = set ? sO : sI;
  int*  bcur = bucketCur + set * NBMAX;
  const int base = blockIdx.x * PACHUNK;
  const int m = min(PACHUNK, E - base);
  const int* bhrow = bh + ((size_t)set * gridDim.x + blockIdx.x) * NBMAX;
  for (int b = t; b < NB; b += 256) cnt[b] = bhrow[b];
  __syncthreads();
  if (t < 64) {
    int carry = 0;
    int nch = (NB + 63) >> 6;
    for (int c = 0; c < nch; ++c) {
      int idx = c * 64 + t;
      int v = (idx < NB) ? cnt[idx] : 0;
      int incl = v;
      #pragma unroll
      for (int d = 1; d < 64; d <<= 1) {
        int u = __shfl_up(incl, d, 64);
        if (t >= d) incl += u;
      }
      if (idx < NB) sb[idx] = carry + incl - v;
      carry += __shfl(incl, 63, 64);
    }
  }
  __syncthreads();
  for (int b = t; b < NB; b += 256) {
    int c = cnt[b];
    if (c > 0) cnt[b] = atomicAdd(&bcur[b], c) - sb[b];
  }
  __syncthreads();
  if (m == PACHUNK && (E & 3) == 0) {
    const int4*   s4 = (const int4*)(ei + base);
    const int4*   d4 = (const int4*)(ei + E + base);
    const float4* w4 = (const float4*)(ew + base);
    #pragma unroll
    for (int r = 0; r < PACHUNK / 1024; ++r) {
      int idx = r * 256 + t;
      int4 sv = s4[idx];
      int4 dv = d4[idx];
      float4 wv = w4[idx];
      {
        int b = dv.x >> 7; int rank = atomicAdd(&sb[b], 1);
        staged[rank] = make_int2(sv.x | ((dv.x & 127) << 16) | (b << 23), __float_as_int(wv.x));
      }
      {
        int b = dv.y >> 7; int rank = atomicAdd(&sb[b], 1);
        staged[rank] = make_int2(sv.y | ((dv.y & 127) << 16) | (b << 23), __float_as_int(wv.y));
      }
      {
        int b = dv.z >> 7; int rank = atomicAdd(&sb[b], 1);
        staged[rank] = make_int2(sv.z | ((dv.z & 127) << 16) | (b << 23), __float_as_int(wv.z));
      }
      {
        int b = dv.w >> 7; int rank = atomicAdd(&sb[b], 1);
        staged[rank] = make_int2(sv.w | ((dv.w & 127) << 16) | (b << 23), __float_as_int(wv.w));
      }
    }
  } else {
    for (int r = 0; r < PACHUNK / 256; ++r) {
      int i = r * 256 + t;
      if (i < m) {
        int src = ei[base + i];
        int dst = ei[E + base + i];
        float w = ew[base + i];
        int b = dst >> 7;
        int rank = atomicAdd(&sb[b], 1);
        staged[rank] = make_int2(src | ((dst & 127) << 16) | (b << 23), __float_as_int(w));
      }
    }
  }
  __syncthreads();
  #pragma unroll 4
  for (int r = 0; r < PACHUNK / 256; ++r) {
    int j = r * 256 + t;
    if (j < m) {
      int2 p = staged[j];
      int b = ((unsigned)p.x) >> 23;
      stg[cnt[b] + j] = p;
    }
  }
}

// ---------------- partB: bucket staging -> per-node offsets (LDS scan) + final CSR order ----------------
// Bucket edges staged in LDS during the counting pass -> single global read (fallback if bucket > PBCAP).
__global__ __launch_bounds__(256) void k_partB(const int* __restrict__ BO, const int* __restrict__ bcur,
                                               const int2* __restrict__ sI, const int2* __restrict__ sO,
                                               int2* __restrict__ eI, int2* __restrict__ eO,
                                               int* __restrict__ offsI, int* __restrict__ offsO, int N) {
  __shared__ int2 se[PBCAP];
  __shared__ int cnt[BSZ];
  __shared__ int excl[BSZ];
  __shared__ int cur[BSZ];
  const int t = threadIdx.x;
  const int b = blockIdx.x;
  const int set = blockIdx.y;
  const int2* stg = set ? sO : sI;
  int2* out = set ? eO : eI;
  int*  offs = set ? offsO : offsI;
  const int nlo = b << 7;
  const int nodes = min(BSZ, N - nlo);
  const int lo = BO[set * NBMAX + b];
  const int hi = bcur[set * NBMAX + b];   // post-partA cursor == bucket end
  const int len = hi - lo;
  const bool fit = (len <= PBCAP);
  if (t < BSZ) cnt[t] = 0;
  __syncthreads();
  if (fit) {
    for (int i = lo + t; i < hi; i += 256) {
      int2 p = stg[i];
      se[i - lo] = p;
      atomicAdd(&cnt[(p.x >> 16) & 127], 1);
    }
  } else {
    for (int i = lo + t; i < hi; i += 256) atomicAdd(&cnt[(stg[i].x >> 16) & 127], 1);
  }
  __syncthreads();
  if (t < 64) {
    int v0 = cnt[t];
    int i0 = v0;
    #pragma unroll
    for (int d = 1; d < 64; d <<= 1) { int u = __shfl_up(i0, d, 64); if (t >= d) i0 += u; }
    int v1 = cnt[64 + t];
    int i1 = v1;
    #pragma unroll
    for (int d = 1; d < 64; d <<= 1) { int u = __shfl_up(i1, d, 64); if (t >= d) i1 += u; }
    int tot0 = __shfl(i0, 63, 64);
    excl[t]      = i0 - v0;
    excl[64 + t] = tot0 + i1 - v1;
  }
  __syncthreads();
  if (t < BSZ) cur[t] = lo + excl[t];
  if (t < nodes) offs[nlo + t] = lo + excl[t];
  if (b == gridDim.x - 1 && t == 0) offs[N] = hi;
  __syncthreads();
  if (fit) {
    for (int i = t; i < len; i += 256) {
      int2 p = se[i];
      int dl = (p.x >> 16) & 127;
      int pos = atomicAdd(&cur[dl], 1);
      out[pos] = make_int2(p.x & 0xffff, p.y);
    }
  } else {
    for (int i = lo + t; i < hi; i += 256) {
      int2 p = stg[i];
      int dl = (p.x >> 16) & 127;
      int pos = atomicAdd(&cur[dl], 1);
      out[pos] = make_int2(p.x & 0xffff, p.y);
    }
  }
}

// ---------------- pack all weights (direct from inputs, summed inline) + bias prep ----------------
// P1's K dimension is PERMUTED to match the LDS layout the fused mf01 kernel writes:
// physical k position p holds logical k = (p&7)*16 + (p>>3).
__device__ inline void pack_one(const float* __restrict__ W, bf16* __restrict__ P,
                                int id, int NT, int DO) {
  int lane = id & 63;
  int tile = id >> 6;
  int nt = tile % NT, kt = tile / NT;
  int col  = nt * 16 + (lane & 15);
  int krow = kt * 32 + (lane >> 4) * 8;
  bf16* dst = P + (size_t)id * 8;
  #pragma unroll
  for (int j = 0; j < 8; ++j) dst[j] = __float2bfloat16(W[(size_t)(krow + j) * DO + col]);
}
__global__ void k_packall(const float* __restrict__ Wmi0, const float* __restrict__ Wmo0,
                          const float* __restrict__ Ws0,
                          const float* __restrict__ Wmi1, const float* __restrict__ Wmo1,
                          const float* __restrict__ Ws1,
                          const float* __restrict__ resW, const float* __restrict__ Wd,
                          const float* __restrict__ bmi0, const float* __restrict__ bsi0,
                          const float* __restrict__ bmo0, const float* __restrict__ bso0,
                          const float* __restrict__ bmi1, const float* __restrict__ bsi1,
                          const float* __restrict__ bmo1, const float* __restrict__ bso1,
                          bf16* __restrict__ P0, bf16* __restrict__ P1, bf16* __restrict__ Pd,
                          float* __restrict__ bi0, float* __restrict__ bo0,
                          float* __restrict__ bi1, float* __restrict__ bo1) {
  int id = blockIdx.x * blockDim.x + threadIdx.x;
  const int T0 = 8 * 8 * 64;    // 256x128 (stacked [Wmi0+Ws0 ; Wmo0+Ws0])
  const int T1 = 4 * 12 * 64;   // 128x192 ([Wmi1+Ws1 | Wmo1+Ws1 | resW]), K permuted
  const int Td = 2 * 8 * 64;    // 64x128
  if (id < T0) {
    int lane = id & 63, tile = id >> 6;
    int nt = tile % 8, kt = tile / 8;
    int col  = nt * 16 + (lane & 15);
    int krow = kt * 32 + (lane >> 4) * 8;
    bf16* dst = P0 + (size_t)id * 8;
    #pragma unroll
    for (int j = 0; j < 8; ++j) {
      int r = krow + j;
      float v = (r < 128 ? Wmi0[r * 128 + col] : Wmo0[(r - 128) * 128 + col])
              + Ws0[(r & 127) * 128 + col];
      dst[j] = __float2bfloat16(v);
    }
  } else if (id < T0 + T1) {
    int id1 = id - T0;
    int lane = id1 & 63, tile = id1 >> 6;
    int nt = tile % 12, kt = tile / 12;
    int col  = nt * 16 + (lane & 15);
    int krow = kt * 32 + (lane >> 4) * 8;
    bf16* dst = P1 + (size_t)id1 * 8;
    #pragma unroll
    for (int j = 0; j < 8; ++j) {
      int kp = krow + j;
      int k = ((kp & 7) << 4) + (kp >> 3);   // inverse of mf01's LDS column permutation
      float v;
      if (col < 64)       v = Wmi1[k * 64 + col]       + Ws1[k * 64 + col];
      else if (col < 128) v = Wmo1[k * 64 + col - 64]  + Ws1[k * 64 + col - 64];
      else                v = resW[k * 64 + col - 128];
      dst[j] = __float2bfloat16(v);
    }
  } else if (id < T0 + T1 + Td) {
    pack_one(Wd, Pd, id - T0 - T1, 8, 128);
  } else {
    int j = id - (T0 + T1 + Td);
    if (j < 128) { bi0[j] = bmi0[j] + bsi0[j]; bo0[j] = bmo0[j] + bso0[j]; }
    if (j < 64)  { bi1[j] = bmi1[j] + bsi1[j]; bo1[j] = bmo1[j] + bso1[j]; }
  }
}

// ---------------- h0 table: bf16(x + pe), row-major [N][128] ----------------
__global__ void k_prep0(const float* __restrict__ x, const float* __restrict__ pe,
                        bf16* __restrict__ h0, int total) {
  int i = blockIdx.x * blockDim.x + threadIdx.x;
  if (i < total) h0[i] = __float2bfloat16(x[i] + pe[i & 127]);
}

// ---------------- layer-0 gather: aggC = [ci*prop_in(h0) | co*prop_out(h0)] (bf16, N x 256) ----------------
// One node per wave. dir = lane>>5, 2 substreams/dir, 16 lanes x 16B uint4 per 256B row.
// 4-deep unroll (empirical optimum); pk-fma accumulation.
__global__ __launch_bounds__(256) void k_agg0(const bf16* __restrict__ tb,
                                              const int* __restrict__ offsI, const int2* __restrict__ eI,
                                              const int* __restrict__ offsO, const int2* __restrict__ eO,
                                              const float* __restrict__ cin, const float* __restrict__ cou,
                                              bf16* __restrict__ aggC, int N) {
  int n = (blockIdx.x * blockDim.x + threadIdx.x) >> 6;
  int lane = threadIdx.x & 63;
  if (n >= N) return;
  const int dir = lane >> 5;
  const int sub = (lane >> 4) & 1;
  const int sl  = lane & 15;
  const int*   offs = dir ? offsO : offsI;
  const int2*  el   = dir ? eO : eI;
  const float* cc   = dir ? cou : cin;
  const char* base = (const char*)tb + sl * 16;
  floatx2 A0 = {0.f, 0.f}, A1 = {0.f, 0.f}, A2 = {0.f, 0.f}, A3 = {0.f, 0.f};
  const int s0 = offs[n], s1 = offs[n + 1];
  int i = s0 + sub;
  for (; i + 6 < s1; i += 8) {
    int2 eA = el[i], eB = el[i + 2], eC = el[i + 4], eD = el[i + 6];
    uint4 vA = *(const uint4*)(base + ((size_t)(unsigned)eA.x << 8));
    uint4 vB = *(const uint4*)(base + ((size_t)(unsigned)eB.x << 8));
    uint4 vC = *(const uint4*)(base + ((size_t)(unsigned)eC.x << 8));
    uint4 vD = *(const uint4*)(base + ((size_t)(unsigned)eD.x << 8));
    float fA = __int_as_float(eA.y), fB = __int_as_float(eB.y);
    float fC = __int_as_float(eC.y), fD = __int_as_float(eD.y);
    floatx2 wA = {fA, fA}, wB = {fB, fB}, wC = {fC, fC}, wD = {fD, fD};
    A0 += wA * bf2_to_f2(vA.x) + wB * bf2_to_f2(vB.x) + wC * bf2_to_f2(vC.x) + wD * bf2_to_f2(vD.x);
    A1 += wA * bf2_to_f2(vA.y) + wB * bf2_to_f2(vB.y) + wC * bf2_to_f2(vC.y) + wD * bf2_to_f2(vD.y);
    A2 += wA * bf2_to_f2(vA.z) + wB * bf2_to_f2(vB.z) + wC * bf2_to_f2(vC.z) + wD * bf2_to_f2(vD.z);
    A3 += wA * bf2_to_f2(vA.w) + wB * bf2_to_f2(vB.w) + wC * bf2_to_f2(vC.w) + wD * bf2_to_f2(vD.w);
  }
  for (; i < s1; i += 2) {
    int2 e = el[i];
    uint4 v = *(const uint4*)(base + ((size_t)(unsigned)e.x << 8));
    float f = __int_as_float(e.y);
    floatx2 w2 = {f, f};
    A0 += w2 * bf2_to_f2(v.x);
    A1 += w2 * bf2_to_f2(v.y);
    A2 += w2 * bf2_to_f2(v.z);
    A3 += w2 * bf2_to_f2(v.w);
  }
  float a0 = A0.x, a1 = A0.y, a2 = A1.x, a3 = A1.y;
  float a4 = A2.x, a5 = A2.y, a6 = A3.x, a7 = A3.y;
  a0 += __shfl_xor(a0, 16, 64); a1 += __shfl_xor(a1, 16, 64);
  a2 += __shfl_xor(a2, 16, 64); a3 += __shfl_xor(a3, 16, 64);
  a4 += __shfl_xor(a4, 16, 64); a5 += __shfl_xor(a5, 16, 64);
  a6 += __shfl_xor(a6, 16, 64); a7 += __shfl_xor(a7, 16, 64);
  if (sub == 0) {
    float c = cc[n];
    uint2 plo = f4_to_bf4(make_float4(c * a0, c * a1, c * a2, c * a3));
    uint2 phi = f4_to_bf4(make_float4(c * a4, c * a5, c * a6, c * a7));
    *(uint4*)(aggC + (size_t)n * 256 + dir * 128 + sl * 8) = make_uint4(plo.x, plo.y, phi.x, phi.y);
  }
}

// ---------------- FUSED layer-0 GEMM + epilogue + layer-1 GEMM ----------------
// GEMM0: aggC(256)@Wp0 -> h1 = tanh(.. + h0), kept in LDS (column-permuted: [row][lc*8+nt]).
// GEMM1: h1(LDS)@Wp1(K-permuted) -> [t1g | t1r]. h1 never touches global memory.
__global__ __launch_bounds__(256) void k_mf01(const bf16* __restrict__ A,
                                              const bf16* __restrict__ Wp0,
                                              const bf16* __restrict__ Wp1,
                                              const float* __restrict__ bi, const float* __restrict__ bo,
                                              const float* __restrict__ cin, const float* __restrict__ cou,
                                              const bf16* __restrict__ h0,
                                              bf16* __restrict__ t1g, bf16* __restrict__ t1r, int N) {
  __shared__ bf16 hs[64][136];   // 272B rows: 16B-aligned, even bank spread
  const int lane = threadIdx.x & 63;
  const int wid  = threadIdx.x >> 6;
  const int quad = lane >> 4, lc = lane & 15;
  const int bmw = blockIdx.x * 64 + wid * 16;
  const int rowc = min(bmw + lc, N - 1);
  // ---- GEMM0 ----
  const bf16* ap = A + (size_t)rowc * 256 + quad * 8;
  const short8* bp = (const short8*)Wp0 + lane;
  floatx4 acc[8] = {};
  #pragma unroll
  for (int kt = 0; kt < 8; ++kt) {
    short8 af = *(const short8*)(ap + kt * 32);
    #pragma unroll
    for (int nt = 0; nt < 8; ++nt) {
      short8 bfr = bp[(kt * 8 + nt) * 64];
      acc[nt] = __builtin_amdgcn_mfma_f32_16x16x32_bf16(af, bfr, acc[nt], 0, 0, 0);
    }
  }
  float bif[8], bof[8];
  #pragma unroll
  for (int nt = 0; nt < 8; ++nt) {
    bif[nt] = bi[nt * 16 + lc];
    bof[nt] = bo[nt * 16 + lc];
  }
  #pragma unroll
  for (int r = 0; r < 4; ++r) {
    int gmc = min(bmw + quad * 4 + r, N - 1);
    float ci = cin[gmc], co = cou[gmc];
    unsigned hp[4];
    #pragma unroll
    for (int np = 0; np < 4; ++np) {
      int n0 = 2 * np, n1 = 2 * np + 1;
      float v0 = acc[n0][r] + ci * bif[n0] + co * bof[n0]
               + __bfloat162float(h0[(size_t)gmc * 128 + n0 * 16 + lc]);
      float v1 = acc[n1][r] + ci * bif[n1] + co * bof[n1]
               + __bfloat162float(h0[(size_t)gmc * 128 + n1 * 16 + lc]);
      bf162 p = __float22bfloat162_rn(make_float2(tanhf(v0), tanhf(v1)));
      hp[np] = *(unsigned*)&p;
    }
    // permuted store: physical col lc*8+nt holds logical col nt*16+lc -> one b128 write
    *(uint4*)(&hs[wid * 16 + quad * 4 + r][lc * 8]) = make_uint4(hp[0], hp[1], hp[2], hp[3]);
  }
  __syncthreads();
  // ---- GEMM1 (A from LDS; Wp1 packed with matching K permutation) ----
  const short8* bp1 = (const short8*)Wp1 + lane;
  floatx4 acc2[12] = {};
  #pragma unroll
  for (int kt = 0; kt < 4; ++kt) {
    short8 af = *(const short8*)(&hs[wid * 16 + lc][kt * 32 + quad * 8]);
    #pragma unroll
    for (int nt = 0; nt < 12; ++nt) {
      short8 bfr = bp1[(kt * 12 + nt) * 64];
      acc2[nt] = __builtin_amdgcn_mfma_f32_16x16x32_bf16(af, bfr, acc2[nt], 0, 0, 0);
    }
  }
  #pragma unroll
  for (int r = 0; r < 4; ++r) {
    int gm = bmw + quad * 4 + r;
    if (gm < N) {
      #pragma unroll
      for (int nt = 0; nt < 12; ++nt) {
        int col = nt * 16 + lc;
        bf16 v = __float2bfloat16(acc2[nt][r]);
        if (col < 128) t1g[(size_t)gm * 128 + col]        = v;
        else           t1r[(size_t)gm * 64 + (col - 128)] = v;
      }
    }
  }
}

// ---------------- layer-1 gather + epilogue -> h2 (bf16), emb (fp32) ----------------
// dir = lane>>5 (in/out concurrent), 4 substreams/dir, 8 lanes x 16B uint4 per 128B dir-row.
// Packed float2 accumulation. Cross-half shfl_xor(32) combines in/out; dir0 writes h2b, dir1 writes emb.
__global__ __launch_bounds__(256) void k_agg1(const bf16* __restrict__ t1g, const bf16* __restrict__ t1r,
                                              const int* __restrict__ offsI, const int2* __restrict__ eI,
                                              const int* __restrict__ offsO, const int2* __restrict__ eO,
                                              const float* __restrict__ bi, const float* __restrict__ bo,
                                              const float* __restrict__ resb,
                                              const float* __restrict__ cin, const float* __restrict__ cou,
                                              bf16* __restrict__ h2b, float* __restrict__ emb, int N) {
  int n = (blockIdx.x * blockDim.x + threadIdx.x) >> 6;
  int lane = threadIdx.x & 63;
  if (n >= N) return;
  const int dir = lane >> 5;
  const int sub = (lane >> 3) & 3;
  const int sl  = lane & 7;
  const int*   offs = dir ? offsO : offsI;
  const int2*  el   = dir ? eO : eI;
  const char* base = (const char*)t1g + dir * 128 + sl * 16;
  floatx2 A0 = {0.f, 0.f}, A1 = {0.f, 0.f}, A2 = {0.f, 0.f}, A3 = {0.f, 0.f};
  const int s0 = offs[n], s1 = offs[n + 1];
  int i = s0 + sub;
  for (; i + 12 < s1; i += 16) {
    int2 eA = el[i], eB = el[i + 4], eC = el[i + 8], eD = el[i + 12];
    uint4 vA = *(const uint4*)(base + ((size_t)(unsigned)eA.x << 8));
    uint4 vB = *(const uint4*)(base + ((size_t)(unsigned)eB.x << 8));
    uint4 vC = *(const uint4*)(base + ((size_t)(unsigned)eC.x << 8));
    uint4 vD = *(const uint4*)(base + ((size_t)(unsigned)eD.x << 8));
    float fA = __int_as_float(eA.y), fB = __int_as_float(eB.y);
    float fC = __int_as_float(eC.y), fD = __int_as_float(eD.y);
    floatx2 wA = {fA, fA}, wB = {fB, fB}, wC = {fC, fC}, wD = {fD, fD};
    A0 += wA * bf2_to_f2(vA.x) + wB * bf2_to_f2(vB.x) + wC * bf2_to_f2(vC.x) + wD * bf2_to_f2(vD.x);
    A1 += wA * bf2_to_f2(vA.y) + wB * bf2_to_f2(vB.y) + wC * bf2_to_f2(vC.y) + wD * bf2_to_f2(vD.y);
    A2 += wA * bf2_to_f2(vA.z) + wB * bf2_to_f2(vB.z) + wC * bf2_to_f2(vC.z) + wD * bf2_to_f2(vD.z);
    A3 += wA * bf2_to_f2(vA.w) + wB * bf2_to_f2(vB.w) + wC * bf2_to_f2(vC.w) + wD * bf2_to_f2(vD.w);
  }
  for (; i < s1; i += 4) {
    int2 e = el[i];
    uint4 v = *(const uint4*)(base + ((size_t)(unsigned)e.x << 8));
    float f = __int_as_float(e.y);
    floatx2 w2 = {f, f};
    A0 += w2 * bf2_to_f2(v.x);
    A1 += w2 * bf2_to_f2(v.y);
    A2 += w2 * bf2_to_f2(v.z);
    A3 += w2 * bf2_to_f2(v.w);
  }
  float a0 = A0.x, a1 = A0.y, a2 = A1.x, a3 = A1.y;
  float a4 = A2.x, a5 = A2.y, a6 = A3.x, a7 = A3.y;
  // reduce over 4 substreams within each 32-lane half
  a0 += __shfl_xor(a0, 8, 64);  a1 += __shfl_xor(a1, 8, 64);
  a2 += __shfl_xor(a2, 8, 64);  a3 += __shfl_xor(a3, 8, 64);
  a4 += __shfl_xor(a4, 8, 64);  a5 += __shfl_xor(a5, 8, 64);
  a6 += __shfl_xor(a6, 8, 64);  a7 += __shfl_xor(a7, 8, 64);
  a0 += __shfl_xor(a0, 16, 64); a1 += __shfl_xor(a1, 16, 64);
  a2 += __shfl_xor(a2, 16, 64); a3 += __shfl_xor(a3, 16, 64);
  a4 += __shfl_xor(a4, 16, 64); a5 += __shfl_xor(a5, 16, 64);
  a6 += __shfl_xor(a6, 16, 64); a7 += __shfl_xor(a7, 16, 64);
  // exchange halves: get the other direction's sums
  float b0 = __shfl_xor(a0, 32, 64), b1 = __shfl_xor(a1, 32, 64);
  float b2 = __shfl_xor(a2, 32, 64), b3 = __shfl_xor(a3, 32, 64);
  float b4 = __shfl_xor(a4, 32, 64), b5 = __shfl_xor(a5, 32, 64);
  float b6 = __shfl_xor(a6, 32, 64), b7 = __shfl_xor(a7, 32, 64);
  if (sub == 0) {
    const int c = sl * 8;
    float ci = cin[n], co = cou[n];
    float s_in[8]  = { dir ? b0 : a0, dir ? b1 : a1, dir ? b2 : a2, dir ? b3 : a3,
                       dir ? b4 : a4, dir ? b5 : a5, dir ? b6 : a6, dir ? b7 : a7 };
    float s_ou[8]  = { dir ? a0 : b0, dir ? a1 : b1, dir ? a2 : b2, dir ? a3 : b3,
                       dir ? a4 : b4, dir ? a5 : b5, dir ? a6 : b6, dir ? a7 : b7 };
    float4 bif0 = *(const float4*)(bi + c),   bif1 = *(const float4*)(bi + c + 4);
    float4 bof0 = *(const float4*)(bo + c),   bof1 = *(const float4*)(bo + c + 4);
    float4 rbf0 = *(const float4*)(resb + c), rbf1 = *(const float4*)(resb + c + 4);
    uint4 rvu = *(const uint4*)((const char*)t1r + (size_t)n * 128 + sl * 16);
    float4 rv0 = bf4_to_f4(make_uint2(rvu.x, rvu.y));
    float4 rv1 = bf4_to_f4(make_uint2(rvu.z, rvu.w));
    float bif[8] = { bif0.x, bif0.y, bif0.z, bif0.w, bif1.x, bif1.y, bif1.z, bif1.w };
    float bof[8] = { bof0.x, bof0.y, bof0.z, bof0.w, bof1.x, bof1.y, bof1.z, bof1.w };
    float rbf[8] = { rbf0.x, rbf0.y, rbf0.z, rbf0.w, rbf1.x, rbf1.y, rbf1.z, rbf1.w };
    float rvf[8] = { rv0.x, rv0.y, rv0.z, rv0.w, rv1.x, rv1.y, rv1.z, rv1.w };
    float v[8];
    float q = 0.f;
    #pragma unroll
    for (int k = 0; k < 8; ++k) {
      v[k] = tanhf(ci * (s_in[k] + bif[k]) + co * (s_ou[k] + bof[k]) + rvf[k] + rbf[k]);
      q += v[k] * v[k];
    }
    q += __shfl_xor(q, 1, 64);
    q += __shfl_xor(q, 2, 64);
    q += __shfl_xor(q, 4, 64);
    if (dir == 0) {
      uint2 plo = f4_to_bf4(make_float4(v[0], v[1], v[2], v[3]));
      uint2 phi = f4_to_bf4(make_float4(v[4], v[5], v[6], v[7]));
      *(uint4*)(h2b + (size_t)n * 64 + c) = make_uint4(plo.x, plo.y, phi.x, phi.y);
    } else {
      float inv = 1.0f / (sqrtf(q) + 1e-12f);
      *(float4*)(emb + (size_t)n * 64 + c)     = make_float4(v[0] * inv, v[1] * inv, v[2] * inv, v[3] * inv);
      *(float4*)(emb + (size_t)n * 64 + c + 4) = make_float4(v[4] * inv, v[5] * inv, v[6] * inv, v[7] * inv);
    }
  }
}

// ---------------- decoder MFMA GEMM + log_softmax ----------------
__global__ __launch_bounds__(256) void k_mfd(const bf16* __restrict__ A,
                                             const bf16* __restrict__ Wp,
                                             const float* __restrict__ bd,
                                             float* __restrict__ logp, int N) {
  const int lane = threadIdx.x & 63;
  const int quad = lane >> 4, lc = lane & 15;
  const int bmw = blockIdx.x * 64 + (threadIdx.x >> 6) * 16;
  const int rowc = min(bmw + lc, N - 1);
  const bf16* ap = A + (size_t)rowc * 64 + quad * 8;
  const short8* bp = (const short8*)Wp + lane;
  floatx4 acc[8] = {};
  #pragma unroll
  for (int kt = 0; kt < 2; ++kt) {
    short8 af = *(const short8*)(ap + kt * 32);
    #pragma unroll
    for (int nt = 0; nt < 8; ++nt) {
      short8 bfr = bp[(kt * 8 + nt) * 64];
      acc[nt] = __builtin_amdgcn_mfma_f32_16x16x32_bf16(af, bfr, acc[nt], 0, 0, 0);
    }
  }
  float bdv[8];
  #pragma unroll
  for (int nt = 0; nt < 8; ++nt) bdv[nt] = bd[nt * 16 + lc];
  #pragma unroll
  for (int r = 0; r < 4; ++r) {
    int gm = bmw + quad * 4 + r;
    float v[8];
    #pragma unroll
    for (int nt = 0; nt < 8; ++nt) v[nt] = acc[nt][r] + bdv[nt];
    float m = v[0];
    #pragma unroll
    for (int nt = 1; nt < 8; ++nt) m = fmaxf(m, v[nt]);
    #pragma unroll
    for (int d = 1; d < 16; d <<= 1) m = fmaxf(m, __shfl_xor(m, d, 64));
    float s = 0.f;
    #pragma unroll
    for (int nt = 0; nt < 8; ++nt) s += __expf(v[nt] - m);
    #pragma unroll
    for (int d = 1; d < 16; d <<= 1) s += __shfl_xor(s, d, 64);
    float lse = m + __logf(s);
    if (gm < N) {
      #pragma unroll
      for (int nt = 0; nt < 8; ++nt) logp[(size_t)gm * 128 + nt * 16 + lc] = v[nt] - lse;
    }
  }
}

extern "C" void kernel_launch(void* const* d_in, const int* in_sizes, int n_in,
                              void* d_out, int out_size, void* d_ws, size_t ws_size,
                              hipStream_t stream) {
  const float* x     = (const float*)d_in[0];
  const int*   ei_in = (const int*)d_in[1];
  const float* ew_in = (const float*)d_in[2];
  const int*   ei_ou = (const int*)d_in[3];
  const float* ew_ou = (const float*)d_in[4];
  const float* pe    = (const float*)d_in[5];
  const float* Wmi0  = (const float*)d_in[6];
  const float* Wmo0  = (const float*)d_in[7];
  const float* Wsh0  = (const float*)d_in[8];
  const float* bmi0  = (const float*)d_in[9];
  const float* bmo0  = (const float*)d_in[10];
  const float* bsi0  = (const float*)d_in[11];
  const float* bso0  = (const float*)d_in[12];
  const float* cin0  = (const float*)d_in[13];
  const float* cou0  = (const float*)d_in[14];
  const float* Wmi1  = (const float*)d_in[15];
  const float* Wmo1  = (const float*)d_in[16];
  const float* Wsh1  = (const float*)d_in[17];
  const float* bmi1  = (const float*)d_in[18];
  const float* bmo1  = (const float*)d_in[19];
  const float* bsi1  = (const float*)d_in[20];
  const float* bso1  = (const float*)d_in[21];
  const float* cin1  = (const float*)d_in[22];
  const float* cou1  = (const float*)d_in[23];
  const float* resW  = (const float*)d_in[24];
  const float* resb  = (const float*)d_in[25];
  const float* Wd    = (const float*)d_in[26];
  const float* bd    = (const float*)d_in[27];

  const int N = in_sizes[0] / 128;
  const int E = in_sizes[2];
  const int NB = (N + BSZ - 1) >> 7;
  const int GCX = (E + PACHUNK - 1) / PACHUNK;

  char* ws = (char*)d_ws;
  size_t off = 0;
  auto alloc = [&](size_t bytes) -> char* {
    off = (off + 255) & ~(size_t)255;
    char* p = ws + off;
    off += bytes;
    return p;
  };
  bf16*  h0bf  = (bf16*)alloc((size_t)N * 128 * 2);
  bf16*  aggC  = (bf16*)alloc((size_t)N * 256 * 2);   // later overlaid by t1g/t1r
  bf16*  h2b   = (bf16*)alloc((size_t)N * 64 * 2);
  bf16*  Wp0   = (bf16*)alloc(256 * 128 * 2);
  bf16*  Wp1   = (bf16*)alloc(128 * 192 * 2);
  bf16*  Wpd   = (bf16*)alloc(64 * 128 * 2);
  float* bi0   = (float*)alloc(128 * 4);
  float* bo0   = (float*)alloc(128 * 4);
  float* bi1   = (float*)alloc(64 * 4);
  float* bo1   = (float*)alloc(64 * 4);
  int*   bcnt  = (int*)alloc((size_t)2 * NBMAX * 4);
  int*   BO    = (int*)alloc((size_t)2 * NBMAX * 4);
  int*   bcur  = (int*)alloc((size_t)2 * NBMAX * 4);
  int*   bh    = (int*)alloc((size_t)2 * GCX * NBMAX * 4);
  int*   offsI = (int*)alloc((size_t)(N + 1) * 4);
  int*   offsO = (int*)alloc((size_t)(N + 1) * 4);
  int2*  sI    = (int2*)alloc((size_t)E * 8);
  int2*  sO    = (int2*)alloc((size_t)E * 8);
  int2*  eI    = (int2*)alloc((size_t)E * 8);
  int2*  eO    = (int2*)alloc((size_t)E * 8);
  bf16* t1g = aggC;                       // overlay: aggC dead after k_mf01's GEMM0
  bf16* t1r = t1g + (size_t)N * 128;

  (void)hipMemsetAsync(bcnt, 0, (size_t)2 * NBMAX * 4, stream);

  dim3 gc(GCX, 2);
  k_bhist<<<gc, 256, 0, stream>>>(ei_in, ei_ou, E, bcnt, bh, NB);
  k_bscan<<<2, 64, 0, stream>>>(bcnt, BO, bcur, NB);
  k_partA<<<gc, 256, 0, stream>>>(ei_in, ew_in, ei_ou, ew_ou, E, bcur, bh, sI, sO, NB);
  dim3 gb(NB, 2);
  k_partB<<<gb, 256, 0, stream>>>(BO, bcur, sI, sO, eI, eO, offsI, offsO, N);
  k_packall<<<(8 * 8 * 64 + 4 * 12 * 64 + 2 * 8 * 64 + 128 + 255) / 256, 256, 0, stream>>>(
      Wmi0, Wmo0, Wsh0, Wmi1, Wmo1, Wsh1, resW, Wd,
      bmi0, bsi0, bmo0, bso0, bmi1, bsi1, bmo1, bso1,
      Wp0, Wp1, Wpd, bi0, bo0, bi1, bo1);
  k_prep0<<<(N * 128 + 255) / 256, 256, 0, stream>>>(x, pe, h0bf, N * 128);

  int ab = (N + 3) / 4;
  int mb = (N + 63) / 64;
  k_agg0<<<ab, 256, 0, stream>>>(h0bf, offsI, eI, offsO, eO, cin0, cou0, aggC, N);
  k_mf01<<<mb, 256, 0, stream>>>(aggC, Wp0, Wp1, bi0, bo0, cin0, cou0, h0bf, t1g, t1r, N);

  float* logp = (float*)d_out;
  float* emb  = logp + (size_t)N * 128;
  k_agg1<<<ab, 256, 0, stream>>>(t1g, t1r, offsI, eI, offsO, eO, bi1, bo1, resb, cin1, cou1,
                                 h2b, emb, N);
  k_mfd<<<mb, 256, 0, stream>>>(h2b, Wpd, bd, logp, N);
}

// Round 12
// 318.199 us; speedup vs baseline: 1.2309x; 1.0490x over previous
//
#include <hip/hip_runtime.h>
#include <hip/hip_bf16.h>
#include <math.h>

typedef __hip_bfloat16  bf16;
typedef __hip_bfloat162 bf162;
typedef __attribute__((ext_vector_type(8))) short short8;   // 8 bf16 = 4 VGPRs
typedef __attribute__((ext_vector_type(4))) float floatx4;  // MFMA acc
typedef __attribute__((ext_vector_type(2))) float floatx2;  // packed f32 (v_pk_fma_f32)

#define BSZ     128
#define NBMAX   512
#define PACHUNK 4096   // 32KB+4KB LDS in partA -> 4 blocks/CU
#define BCAP    3072   // fixed edge capacity per 128-node bucket (mean 2048, P(>3072)~e^-200)

__device__ inline float4 bf4_to_f4(uint2 v) {
  float2 lo = __bfloat1622float2(*(bf162*)&v.x);
  float2 hi = __bfloat1622float2(*(bf162*)&v.y);
  return make_float4(lo.x, lo.y, hi.x, hi.y);
}
__device__ inline uint2 f4_to_bf4(float4 v) {
  bf162 lo = __float22bfloat162_rn(make_float2(v.x, v.y));
  bf162 hi = __float22bfloat162_rn(make_float2(v.z, v.w));
  uint2 r;
  r.x = *(unsigned*)&lo;
  r.y = *(unsigned*)&hi;
  return r;
}
// one bf162 word -> packed float2 {lo, hi}
__device__ inline floatx2 bf2_to_f2(unsigned u) {
  floatx2 r;
  r.x = __uint_as_float(u << 16);
  r.y = __uint_as_float(u & 0xffff0000u);
  return r;
}

// ---------------- partA: counting-sort edges into FIXED-SLOT bucket staging ----------------
// No global histogram/scan needed: bucket b owns slot [b*BCAP, (b+1)*BCAP); chunks claim
// sub-ranges via atomicAdd(bcur[b]). Local LDS histogram + scan orders the chunk's edges.
__global__ __launch_bounds__(256) void k_partA(const int* __restrict__ eiIn, const float* __restrict__ ewIn,
                                               const int* __restrict__ eiOut, const float* __restrict__ ewOut,
                                               int E, int* __restrict__ bucketCur,
                                               int2* __restrict__ sI, int2* __restrict__ sO, int NB) {
  __shared__ int2 staged[PACHUNK];
  __shared__ int cnt[NBMAX];
  __shared__ int sb[NBMAX];
  const int t = threadIdx.x;
  const int set = blockIdx.y;
  const int*   ei = set ? eiOut : eiIn;
  const float* ew = set ? ewOut : ewIn;
  int2* stg  = set ? sO : sI;
  int*  bcur = bucketCur + set * NBMAX;
  const int base = blockIdx.x * PACHUNK;
  const int m = min(PACHUNK, E - base);
  const bool vec = (m == PACHUNK) && ((E & 3) == 0);
  for (int b = t; b < NB; b += 256) cnt[b] = 0;
  __syncthreads();
  if (vec) {
    const int4* d4 = (const int4*)(ei + E + base);
    #pragma unroll
    for (int r = 0; r < PACHUNK / 1024; ++r) {
      int4 v = d4[r * 256 + t];
      atomicAdd(&cnt[v.x >> 7], 1);
      atomicAdd(&cnt[v.y >> 7], 1);
      atomicAdd(&cnt[v.z >> 7], 1);
      atomicAdd(&cnt[v.w >> 7], 1);
    }
  } else {
    for (int r = 0; r < PACHUNK / 256; ++r) {
      int i = r * 256 + t;
      if (i < m) atomicAdd(&cnt[ei[E + base + i] >> 7], 1);
    }
  }
  __syncthreads();
  if (t < 64) {
    int carry = 0;
    int nch = (NB + 63) >> 6;
    for (int c = 0; c < nch; ++c) {
      int idx = c * 64 + t;
      int v = (idx < NB) ? cnt[idx] : 0;
      int incl = v;
      #pragma unroll
      for (int d = 1; d < 64; d <<= 1) {
        int u = __shfl_up(incl, d, 64);
        if (t >= d) incl += u;
      }
      if (idx < NB) sb[idx] = carry + incl - v;
      carry += __shfl(incl, 63, 64);
    }
  }
  __syncthreads();
  for (int b = t; b < NB; b += 256) {
    int c = cnt[b];
    if (c > 0) cnt[b] = b * BCAP + atomicAdd(&bcur[b], c) - sb[b];
  }
  __syncthreads();
  if (vec) {
    const int4*   s4 = (const int4*)(ei + base);
    const int4*   d4 = (const int4*)(ei + E + base);
    const float4* w4 = (const float4*)(ew + base);
    #pragma unroll
    for (int r = 0; r < PACHUNK / 1024; ++r) {
      int idx = r * 256 + t;
      int4 sv = s4[idx];
      int4 dv = d4[idx];
      float4 wv = w4[idx];
      {
        int b = dv.x >> 7; int rank = atomicAdd(&sb[b], 1);
        staged[rank] = make_int2(sv.x | ((dv.x & 127) << 16) | (b << 23), __float_as_int(wv.x));
      }
      {
        int b = dv.y >> 7; int rank = atomicAdd(&sb[b], 1);
        staged[rank] = make_int2(sv.y | ((dv.y & 127) << 16) | (b << 23), __float_as_int(wv.y));
      }
      {
        int b = dv.z >> 7; int rank = atomicAdd(&sb[b], 1);
        staged[rank] = make_int2(sv.z | ((dv.z & 127) << 16) | (b << 23), __float_as_int(wv.z));
      }
      {
        int b = dv.w >> 7; int rank = atomicAdd(&sb[b], 1);
        staged[rank] = make_int2(sv.w | ((dv.w & 127) << 16) | (b << 23), __float_as_int(wv.w));
      }
    }
  } else {
    for (int r = 0; r < PACHUNK / 256; ++r) {
      int i = r * 256 + t;
      if (i < m) {
        int src = ei[base + i];
        int dst = ei[E + base + i];
        float w = ew[base + i];
        int b = dst >> 7;
        int rank = atomicAdd(&sb[b], 1);
        staged[rank] = make_int2(src | ((dst & 127) << 16) | (b << 23), __float_as_int(w));
      }
    }
  }
  __syncthreads();
  #pragma unroll 4
  for (int r = 0; r < PACHUNK / 256; ++r) {
    int j = r * 256 + t;
    if (j < m) {
      int2 p = staged[j];
      int b = ((unsigned)p.x) >> 23;
      stg[cnt[b] + j] = p;
    }
  }
}

// ---------------- partB: bucket slot -> per-node {start,end} offsets + final CSR order ----------------
// Bucket always fits LDS (len<=BCAP). Output ALIASES the staging buffer: all reads complete
// into LDS before the scatter writes. Offsets are absolute into the slot space.
__global__ __launch_bounds__(256) void k_partB(const int* __restrict__ bcur,
                                               const int2* __restrict__ sI, const int2* __restrict__ sO,
                                               int2* __restrict__ eI, int2* __restrict__ eO,
                                               int2* __restrict__ offsPI, int2* __restrict__ offsPO, int N) {
  __shared__ int2 se[BCAP];
  __shared__ int cnt[BSZ];
  __shared__ int excl[BSZ];
  __shared__ int cur[BSZ];
  const int t = threadIdx.x;
  const int b = blockIdx.x;
  const int set = blockIdx.y;
  const int2* stg = set ? sO : sI;
  int2* out = set ? eO : eI;
  int2* offsP = set ? offsPO : offsPI;
  const int nlo = b << 7;
  const int nodes = min(BSZ, N - nlo);
  const int lo = b * BCAP;
  const int len = min(bcur[set * NBMAX + b], BCAP);
  if (t < BSZ) cnt[t] = 0;
  __syncthreads();
  for (int i = t; i < len; i += 256) {
    int2 p = stg[lo + i];
    se[i] = p;
    atomicAdd(&cnt[(p.x >> 16) & 127], 1);
  }
  __syncthreads();
  if (t < 64) {
    int v0 = cnt[t];
    int i0 = v0;
    #pragma unroll
    for (int d = 1; d < 64; d <<= 1) { int u = __shfl_up(i0, d, 64); if (t >= d) i0 += u; }
    int v1 = cnt[64 + t];
    int i1 = v1;
    #pragma unroll
    for (int d = 1; d < 64; d <<= 1) { int u = __shfl_up(i1, d, 64); if (t >= d) i1 += u; }
    int tot0 = __shfl(i0, 63, 64);
    excl[t]      = i0 - v0;
    excl[64 + t] = tot0 + i1 - v1;
  }
  __syncthreads();
  if (t < BSZ) cur[t] = lo + excl[t];
  if (t < nodes) offsP[nlo + t] = make_int2(lo + excl[t], lo + excl[t] + cnt[t]);
  __syncthreads();
  for (int i = t; i < len; i += 256) {
    int2 p = se[i];
    int dl = (p.x >> 16) & 127;
    int pos = atomicAdd(&cur[dl], 1);
    out[pos] = make_int2(p.x & 0xffff, p.y);
  }
}

// ---------------- FUSED: weight pack (+bias prep) + h0 table ----------------
// P1's K dimension is PERMUTED to match mf01's LDS layout: physical k p holds logical
// k = (p&7)*16 + (p>>3). Low thread-ids additionally do the pack work.
__device__ inline void pack_one(const float* __restrict__ W, bf16* __restrict__ P,
                                int id, int NT, int DO) {
  int lane = id & 63;
  int tile = id >> 6;
  int nt = tile % NT, kt = tile / NT;
  int col  = nt * 16 + (lane & 15);
  int krow = kt * 32 + (lane >> 4) * 8;
  bf16* dst = P + (size_t)id * 8;
  #pragma unroll
  for (int j = 0; j < 8; ++j) dst[j] = __float2bfloat16(W[(size_t)(krow + j) * DO + col]);
}
__global__ void k_prep(const float* __restrict__ x, const float* __restrict__ pe,
                       bf16* __restrict__ h0, int total,
                       const float* __restrict__ Wmi0, const float* __restrict__ Wmo0,
                       const float* __restrict__ Ws0,
                       const float* __restrict__ Wmi1, const float* __restrict__ Wmo1,
                       const float* __restrict__ Ws1,
                       const float* __restrict__ resW, const float* __restrict__ Wd,
                       const float* __restrict__ bmi0, const float* __restrict__ bsi0,
                       const float* __restrict__ bmo0, const float* __restrict__ bso0,
                       const float* __restrict__ bmi1, const float* __restrict__ bsi1,
                       const float* __restrict__ bmo1, const float* __restrict__ bso1,
                       bf16* __restrict__ P0, bf16* __restrict__ P1, bf16* __restrict__ Pd,
                       float* __restrict__ bi0, float* __restrict__ bo0,
                       float* __restrict__ bi1, float* __restrict__ bo1) {
  int id = blockIdx.x * blockDim.x + threadIdx.x;
  const int T0 = 8 * 8 * 64;    // 256x128 (stacked [Wmi0+Ws0 ; Wmo0+Ws0])
  const int T1 = 4 * 12 * 64;   // 128x192 ([Wmi1+Ws1 | Wmo1+Ws1 | resW]), K permuted
  const int Td = 2 * 8 * 64;    // 64x128
  if (id < T0) {
    int lane = id & 63, tile = id >> 6;
    int nt = tile % 8, kt = tile / 8;
    int col  = nt * 16 + (lane & 15);
    int krow = kt * 32 + (lane >> 4) * 8;
    bf16* dst = P0 + (size_t)id * 8;
    #pragma unroll
    for (int j = 0; j < 8; ++j) {
      int r = krow + j;
      float v = (r < 128 ? Wmi0[r * 128 + col] : Wmo0[(r - 128) * 128 + col])
              + Ws0[(r & 127) * 128 + col];
      dst[j] = __float2bfloat16(v);
    }
  } else if (id < T0 + T1) {
    int id1 = id - T0;
    int lane = id1 & 63, tile = id1 >> 6;
    int nt = tile % 12, kt = tile / 12;
    int col  = nt * 16 + (lane & 15);
    int krow = kt * 32 + (lane >> 4) * 8;
    bf16* dst = P1 + (size_t)id1 * 8;
    #pragma unroll
    for (int j = 0; j < 8; ++j) {
      int kp = krow + j;
      int k = ((kp & 7) << 4) + (kp >> 3);   // inverse of mf01's LDS column permutation
      float v;
      if (col < 64)       v = Wmi1[k * 64 + col]       + Ws1[k * 64 + col];
      else if (col < 128) v = Wmo1[k * 64 + col - 64]  + Ws1[k * 64 + col - 64];
      else                v = resW[k * 64 + col - 128];
      dst[j] = __float2bfloat16(v);
    }
  } else if (id < T0 + T1 + Td) {
    pack_one(Wd, Pd, id - T0 - T1, 8, 128);
  } else if (id < T0 + T1 + Td + 128) {
    int j = id - (T0 + T1 + Td);
    if (j < 128) { bi0[j] = bmi0[j] + bsi0[j]; bo0[j] = bmo0[j] + bso0[j]; }
    if (j < 64)  { bi1[j] = bmi1[j] + bsi1[j]; bo1[j] = bmo1[j] + bso1[j]; }
  }
  if (id < total) h0[id] = __float2bfloat16(x[id] + pe[id & 127]);
}

// ---------------- layer-0 gather: aggC = [ci*prop_in(h0) | co*prop_out(h0)] (bf16, N x 256) ----------------
// One node per wave. dir = lane>>5, 2 substreams/dir, 16 lanes x 16B uint4 per 256B row.
// 4-deep unroll (empirical optimum); pk-fma accumulation. Offsets are {start,end} int2.
__global__ __launch_bounds__(256) void k_agg0(const bf16* __restrict__ tb,
                                              const int2* __restrict__ offsPI, const int2* __restrict__ eI,
                                              const int2* __restrict__ offsPO, const int2* __restrict__ eO,
                                              const float* __restrict__ cin, const float* __restrict__ cou,
                                              bf16* __restrict__ aggC, int N) {
  int n = (blockIdx.x * blockDim.x + threadIdx.x) >> 6;
  int lane = threadIdx.x & 63;
  if (n >= N) return;
  const int dir = lane >> 5;
  const int sub = (lane >> 4) & 1;
  const int sl  = lane & 15;
  const int2* offsP = dir ? offsPO : offsPI;
  const int2* el    = dir ? eO : eI;
  const float* cc   = dir ? cou : cin;
  const char* base = (const char*)tb + sl * 16;
  floatx2 A0 = {0.f, 0.f}, A1 = {0.f, 0.f}, A2 = {0.f, 0.f}, A3 = {0.f, 0.f};
  const int2 sp = offsP[n];
  const int s0 = sp.x, s1 = sp.y;
  int i = s0 + sub;
  for (; i + 6 < s1; i += 8) {
    int2 eA = el[i], eB = el[i + 2], eC = el[i + 4], eD = el[i + 6];
    uint4 vA = *(const uint4*)(base + ((size_t)(unsigned)eA.x << 8));
    uint4 vB = *(const uint4*)(base + ((size_t)(unsigned)eB.x << 8));
    uint4 vC = *(const uint4*)(base + ((size_t)(unsigned)eC.x << 8));
    uint4 vD = *(const uint4*)(base + ((size_t)(unsigned)eD.x << 8));
    float fA = __int_as_float(eA.y), fB = __int_as_float(eB.y);
    float fC = __int_as_float(eC.y), fD = __int_as_float(eD.y);
    floatx2 wA = {fA, fA}, wB = {fB, fB}, wC = {fC, fC}, wD = {fD, fD};
    A0 += wA * bf2_to_f2(vA.x) + wB * bf2_to_f2(vB.x) + wC * bf2_to_f2(vC.x) + wD * bf2_to_f2(vD.x);
    A1 += wA * bf2_to_f2(vA.y) + wB * bf2_to_f2(vB.y) + wC * bf2_to_f2(vC.y) + wD * bf2_to_f2(vD.y);
    A2 += wA * bf2_to_f2(vA.z) + wB * bf2_to_f2(vB.z) + wC * bf2_to_f2(vC.z) + wD * bf2_to_f2(vD.z);
    A3 += wA * bf2_to_f2(vA.w) + wB * bf2_to_f2(vB.w) + wC * bf2_to_f2(vC.w) + wD * bf2_to_f2(vD.w);
  }
  for (; i < s1; i += 2) {
    int2 e = el[i];
    uint4 v = *(const uint4*)(base + ((size_t)(unsigned)e.x << 8));
    float f = __int_as_float(e.y);
    floatx2 w2 = {f, f};
    A0 += w2 * bf2_to_f2(v.x);
    A1 += w2 * bf2_to_f2(v.y);
    A2 += w2 * bf2_to_f2(v.z);
    A3 += w2 * bf2_to_f2(v.w);
  }
  float a0 = A0.x, a1 = A0.y, a2 = A1.x, a3 = A1.y;
  float a4 = A2.x, a5 = A2.y, a6 = A3.x, a7 = A3.y;
  a0 += __shfl_xor(a0, 16, 64); a1 += __shfl_xor(a1, 16, 64);
  a2 += __shfl_xor(a2, 16, 64); a3 += __shfl_xor(a3, 16, 64);
  a4 += __shfl_xor(a4, 16, 64); a5 += __shfl_xor(a5, 16, 64);
  a6 += __shfl_xor(a6, 16, 64); a7 += __shfl_xor(a7, 16, 64);
  if (sub == 0) {
    float c = cc[n];
    uint2 plo = f4_to_bf4(make_float4(c * a0, c * a1, c * a2, c * a3));
    uint2 phi = f4_to_bf4(make_float4(c * a4, c * a5, c * a6, c * a7));
    *(uint4*)(aggC + (size_t)n * 256 + dir * 128 + sl * 8) = make_uint4(plo.x, plo.y, phi.x, phi.y);
  }
}

// ---------------- FUSED layer-0 GEMM + epilogue + layer-1 GEMM ----------------
__global__ __launch_bounds__(256) void k_mf01(const bf16* __restrict__ A,
                                              const bf16* __restrict__ Wp0,
                                              const bf16* __restrict__ Wp1,
                                              const float* __restrict__ bi, const float* __restrict__ bo,
                                              const float* __restrict__ cin, const float* __restrict__ cou,
                                              const bf16* __restrict__ h0,
                                              bf16* __restrict__ t1g, bf16* __restrict__ t1r, int N) {
  __shared__ bf16 hs[64][136];   // 272B rows: 16B-aligned, even bank spread
  const int lane = threadIdx.x & 63;
  const int wid  = threadIdx.x >> 6;
  const int quad = lane >> 4, lc = lane & 15;
  const int bmw = blockIdx.x * 64 + wid * 16;
  const int rowc = min(bmw + lc, N - 1);
  // ---- GEMM0 ----
  const bf16* ap = A + (size_t)rowc * 256 + quad * 8;
  const short8* bp = (const short8*)Wp0 + lane;
  floatx4 acc[8] = {};
  #pragma unroll
  for (int kt = 0; kt < 8; ++kt) {
    short8 af = *(const short8*)(ap + kt * 32);
    #pragma unroll
    for (int nt = 0; nt < 8; ++nt) {
      short8 bfr = bp[(kt * 8 + nt) * 64];
      acc[nt] = __builtin_amdgcn_mfma_f32_16x16x32_bf16(af, bfr, acc[nt], 0, 0, 0);
    }
  }
  float bif[8], bof[8];
  #pragma unroll
  for (int nt = 0; nt < 8; ++nt) {
    bif[nt] = bi[nt * 16 + lc];
    bof[nt] = bo[nt * 16 + lc];
  }
  #pragma unroll
  for (int r = 0; r < 4; ++r) {
    int gmc = min(bmw + quad * 4 + r, N - 1);
    float ci = cin[gmc], co = cou[gmc];
    unsigned hp[4];
    #pragma unroll
    for (int np = 0; np < 4; ++np) {
      int n0 = 2 * np, n1 = 2 * np + 1;
      float v0 = acc[n0][r] + ci * bif[n0] + co * bof[n0]
               + __bfloat162float(h0[(size_t)gmc * 128 + n0 * 16 + lc]);
      float v1 = acc[n1][r] + ci * bif[n1] + co * bof[n1]
               + __bfloat162float(h0[(size_t)gmc * 128 + n1 * 16 + lc]);
      bf162 p = __float22bfloat162_rn(make_float2(tanhf(v0), tanhf(v1)));
      hp[np] = *(unsigned*)&p;
    }
    *(uint4*)(&hs[wid * 16 + quad * 4 + r][lc * 8]) = make_uint4(hp[0], hp[1], hp[2], hp[3]);
  }
  __syncthreads();
  // ---- GEMM1 (A from LDS; Wp1 packed with matching K permutation) ----
  const short8* bp1 = (const short8*)Wp1 + lane;
  floatx4 acc2[12] = {};
  #pragma unroll
  for (int kt = 0; kt < 4; ++kt) {
    short8 af = *(const short8*)(&hs[wid * 16 + lc][kt * 32 + quad * 8]);
    #pragma unroll
    for (int nt = 0; nt < 12; ++nt) {
      short8 bfr = bp1[(kt * 12 + nt) * 64];
      acc2[nt] = __builtin_amdgcn_mfma_f32_16x16x32_bf16(af, bfr, acc2[nt], 0, 0, 0);
    }
  }
  #pragma unroll
  for (int r = 0; r < 4; ++r) {
    int gm = bmw + quad * 4 + r;
    if (gm < N) {
      #pragma unroll
      for (int nt = 0; nt < 12; ++nt) {
        int col = nt * 16 + lc;
        bf16 v = __float2bfloat16(acc2[nt][r]);
        if (col < 128) t1g[(size_t)gm * 128 + col]        = v;
        else           t1r[(size_t)gm * 64 + (col - 128)] = v;
      }
    }
  }
}

// ---------------- layer-1 gather + epilogue -> h2 (bf16), emb (fp32) ----------------
__global__ __launch_bounds__(256) void k_agg1(const bf16* __restrict__ t1g, const bf16* __restrict__ t1r,
                                              const int2* __restrict__ offsPI, const int2* __restrict__ eI,
                                              const int2* __restrict__ offsPO, const int2* __restrict__ eO,
                                              const float* __restrict__ bi, const float* __restrict__ bo,
                                              const float* __restrict__ resb,
                                              const float* __restrict__ cin, const float* __restrict__ cou,
                                              bf16* __restrict__ h2b, float* __restrict__ emb, int N) {
  int n = (blockIdx.x * blockDim.x + threadIdx.x) >> 6;
  int lane = threadIdx.x & 63;
  if (n >= N) return;
  const int dir = lane >> 5;
  const int sub = (lane >> 3) & 3;
  const int sl  = lane & 7;
  const int2* offsP = dir ? offsPO : offsPI;
  const int2* el    = dir ? eO : eI;
  const char* base = (const char*)t1g + dir * 128 + sl * 16;
  floatx2 A0 = {0.f, 0.f}, A1 = {0.f, 0.f}, A2 = {0.f, 0.f}, A3 = {0.f, 0.f};
  const int2 sp = offsP[n];
  const int s0 = sp.x, s1 = sp.y;
  int i = s0 + sub;
  for (; i + 12 < s1; i += 16) {
    int2 eA = el[i], eB = el[i + 4], eC = el[i + 8], eD = el[i + 12];
    uint4 vA = *(const uint4*)(base + ((size_t)(unsigned)eA.x << 8));
    uint4 vB = *(const uint4*)(base + ((size_t)(unsigned)eB.x << 8));
    uint4 vC = *(const uint4*)(base + ((size_t)(unsigned)eC.x << 8));
    uint4 vD = *(const uint4*)(base + ((size_t)(unsigned)eD.x << 8));
    float fA = __int_as_float(eA.y), fB = __int_as_float(eB.y);
    float fC = __int_as_float(eC.y), fD = __int_as_float(eD.y);
    floatx2 wA = {fA, fA}, wB = {fB, fB}, wC = {fC, fC}, wD = {fD, fD};
    A0 += wA * bf2_to_f2(vA.x) + wB * bf2_to_f2(vB.x) + wC * bf2_to_f2(vC.x) + wD * bf2_to_f2(vD.x);
    A1 += wA * bf2_to_f2(vA.y) + wB * bf2_to_f2(vB.y) + wC * bf2_to_f2(vC.y) + wD * bf2_to_f2(vD.y);
    A2 += wA * bf2_to_f2(vA.z) + wB * bf2_to_f2(vB.z) + wC * bf2_to_f2(vC.z) + wD * bf2_to_f2(vD.z);
    A3 += wA * bf2_to_f2(vA.w) + wB * bf2_to_f2(vB.w) + wC * bf2_to_f2(vC.w) + wD * bf2_to_f2(vD.w);
  }
  for (; i < s1; i += 4) {
    int2 e = el[i];
    uint4 v = *(const uint4*)(base + ((size_t)(unsigned)e.x << 8));
    float f = __int_as_float(e.y);
    floatx2 w2 = {f, f};
    A0 += w2 * bf2_to_f2(v.x);
    A1 += w2 * bf2_to_f2(v.y);
    A2 += w2 * bf2_to_f2(v.z);
    A3 += w2 * bf2_to_f2(v.w);
  }
  float a0 = A0.x, a1 = A0.y, a2 = A1.x, a3 = A1.y;
  float a4 = A2.x, a5 = A2.y, a6 = A3.x, a7 = A3.y;
  a0 += __shfl_xor(a0, 8, 64);  a1 += __shfl_xor(a1, 8, 64);
  a2 += __shfl_xor(a2, 8, 64);  a3 += __shfl_xor(a3, 8, 64);
  a4 += __shfl_xor(a4, 8, 64);  a5 += __shfl_xor(a5, 8, 64);
  a6 += __shfl_xor(a6, 8, 64);  a7 += __shfl_xor(a7, 8, 64);
  a0 += __shfl_xor(a0, 16, 64); a1 += __shfl_xor(a1, 16, 64);
  a2 += __shfl_xor(a2, 16, 64); a3 += __shfl_xor(a3, 16, 64);
  a4 += __shfl_xor(a4, 16, 64); a5 += __shfl_xor(a5, 16, 64);
  a6 += __shfl_xor(a6, 16, 64); a7 += __shfl_xor(a7, 16, 64);
  float b0 = __shfl_xor(a0, 32, 64), b1 = __shfl_xor(a1, 32, 64);
  float b2 = __shfl_xor(a2, 32, 64), b3 = __shfl_xor(a3, 32, 64);
  float b4 = __shfl_xor(a4, 32, 64), b5 = __shfl_xor(a5, 32, 64);
  float b6 = __shfl_xor(a6, 32, 64), b7 = __shfl_xor(a7, 32, 64);
  if (sub == 0) {
    const int c = sl * 8;
    float ci = cin[n], co = cou[n];
    float s_in[8]  = { dir ? b0 : a0, dir ? b1 : a1, dir ? b2 : a2, dir ? b3 : a3,
                       dir ? b4 : a4, dir ? b5 : a5, dir ? b6 : a6, dir ? b7 : a7 };
    float s_ou[8]  = { dir ? a0 : b0, dir ? a1 : b1, dir ? a2 : b2, dir ? a3 : b3,
                       dir ? a4 : b4, dir ? a5 : b5, dir ? a6 : b6, dir ? a7 : b7 };
    float4 bif0 = *(const float4*)(bi + c),   bif1 = *(const float4*)(bi + c + 4);
    float4 bof0 = *(const float4*)(bo + c),   bof1 = *(const float4*)(bo + c + 4);
    float4 rbf0 = *(const float4*)(resb + c), rbf1 = *(const float4*)(resb + c + 4);
    uint4 rvu = *(const uint4*)((const char*)t1r + (size_t)n * 128 + sl * 16);
    float4 rv0 = bf4_to_f4(make_uint2(rvu.x, rvu.y));
    float4 rv1 = bf4_to_f4(make_uint2(rvu.z, rvu.w));
    float bif[8] = { bif0.x, bif0.y, bif0.z, bif0.w, bif1.x, bif1.y, bif1.z, bif1.w };
    float bof[8] = { bof0.x, bof0.y, bof0.z, bof0.w, bof1.x, bof1.y, bof1.z, bof1.w };
    float rbf[8] = { rbf0.x, rbf0.y, rbf0.z, rbf0.w, rbf1.x, rbf1.y, rbf1.z, rbf1.w };
    float rvf[8] = { rv0.x, rv0.y, rv0.z, rv0.w, rv1.x, rv1.y, rv1.z, rv1.w };
    float v[8];
    float q = 0.f;
    #pragma unroll
    for (int k = 0; k < 8; ++k) {
      v[k] = tanhf(ci * (s_in[k] + bif[k]) + co * (s_ou[k] + bof[k]) + rvf[k] + rbf[k]);
      q += v[k] * v[k];
    }
    q += __shfl_xor(q, 1, 64);
    q += __shfl_xor(q, 2, 64);
    q += __shfl_xor(q, 4, 64);
    if (dir == 0) {
      uint2 plo = f4_to_bf4(make_float4(v[0], v[1], v[2], v[3]));
      uint2 phi = f4_to_bf4(make_float4(v[4], v[5], v[6], v[7]));
      *(uint4*)(h2b + (size_t)n * 64 + c) = make_uint4(plo.x, plo.y, phi.x, phi.y);
    } else {
      float inv = 1.0f / (sqrtf(q) + 1e-12f);
      *(float4*)(emb + (size_t)n * 64 + c)     = make_float4(v[0] * inv, v[1] * inv, v[2] * inv, v[3] * inv);
      *(float4*)(emb + (size_t)n * 64 + c + 4) = make_float4(v[4] * inv, v[5] * inv, v[6] * inv, v[7] * inv);
    }
  }
}

// ---------------- decoder MFMA GEMM + log_softmax ----------------
__global__ __launch_bounds__(256) void k_mfd(const bf16* __restrict__ A,
                                             const bf16* __restrict__ Wp,
                                             const float* __restrict__ bd,
                                             float* __restrict__ logp, int N) {
  const int lane = threadIdx.x & 63;
  const int quad = lane >> 4, lc = lane & 15;
  const int bmw = blockIdx.x * 64 + (threadIdx.x >> 6) * 16;
  const int rowc = min(bmw + lc, N - 1);
  const bf16* ap = A + (size_t)rowc * 64 + quad * 8;
  const short8* bp = (const short8*)Wp + lane;
  floatx4 acc[8] = {};
  #pragma unroll
  for (int kt = 0; kt < 2; ++kt) {
    short8 af = *(const short8*)(ap + kt * 32);
    #pragma unroll
    for (int nt = 0; nt < 8; ++nt) {
      short8 bfr = bp[(kt * 8 + nt) * 64];
      acc[nt] = __builtin_amdgcn_mfma_f32_16x16x32_bf16(af, bfr, acc[nt], 0, 0, 0);
    }
  }
  float bdv[8];
  #pragma unroll
  for (int nt = 0; nt < 8; ++nt) bdv[nt] = bd[nt * 16 + lc];
  #pragma unroll
  for (int r = 0; r < 4; ++r) {
    int gm = bmw + quad * 4 + r;
    float v[8];
    #pragma unroll
    for (int nt = 0; nt < 8; ++nt) v[nt] = acc[nt][r] + bdv[nt];
    float m = v[0];
    #pragma unroll
    for (int nt = 1; nt < 8; ++nt) m = fmaxf(m, v[nt]);
    #pragma unroll
    for (int d = 1; d < 16; d <<= 1) m = fmaxf(m, __shfl_xor(m, d, 64));
    float s = 0.f;
    #pragma unroll
    for (int nt = 0; nt < 8; ++nt) s += __expf(v[nt] - m);
    #pragma unroll
    for (int d = 1; d < 16; d <<= 1) s += __shfl_xor(s, d, 64);
    float lse = m + __logf(s);
    if (gm < N) {
      #pragma unroll
      for (int nt = 0; nt < 8; ++nt) logp[(size_t)gm * 128 + nt * 16 + lc] = v[nt] - lse;
    }
  }
}

extern "C" void kernel_launch(void* const* d_in, const int* in_sizes, int n_in,
                              void* d_out, int out_size, void* d_ws, size_t ws_size,
                              hipStream_t stream) {
  const float* x     = (const float*)d_in[0];
  const int*   ei_in = (const int*)d_in[1];
  const float* ew_in = (const float*)d_in[2];
  const int*   ei_ou = (const int*)d_in[3];
  const float* ew_ou = (const float*)d_in[4];
  const float* pe    = (const float*)d_in[5];
  const float* Wmi0  = (const float*)d_in[6];
  const float* Wmo0  = (const float*)d_in[7];
  const float* Wsh0  = (const float*)d_in[8];
  const float* bmi0  = (const float*)d_in[9];
  const float* bmo0  = (const float*)d_in[10];
  const float* bsi0  = (const float*)d_in[11];
  const float* bso0  = (const float*)d_in[12];
  const float* cin0  = (const float*)d_in[13];
  const float* cou0  = (const float*)d_in[14];
  const float* Wmi1  = (const float*)d_in[15];
  const float* Wmo1  = (const float*)d_in[16];
  const float* Wsh1  = (const float*)d_in[17];
  const float* bmi1  = (const float*)d_in[18];
  const float* bmo1  = (const float*)d_in[19];
  const float* bsi1  = (const float*)d_in[20];
  const float* bso1  = (const float*)d_in[21];
  const float* cin1  = (const float*)d_in[22];
  const float* cou1  = (const float*)d_in[23];
  const float* resW  = (const float*)d_in[24];
  const float* resb  = (const float*)d_in[25];
  const float* Wd    = (const float*)d_in[26];
  const float* bd    = (const float*)d_in[27];

  const int N = in_sizes[0] / 128;
  const int E = in_sizes[2];
  const int NB = (N + BSZ - 1) >> 7;
  const int GCX = (E + PACHUNK - 1) / PACHUNK;

  char* ws = (char*)d_ws;
  size_t off = 0;
  auto alloc = [&](size_t bytes) -> char* {
    off = (off + 255) & ~(size_t)255;
    char* p = ws + off;
    off += bytes;
    return p;
  };
  bf16*  h0bf  = (bf16*)alloc((size_t)N * 128 * 2);
  bf16*  aggC  = (bf16*)alloc((size_t)N * 256 * 2);   // later overlaid by t1g/t1r
  bf16*  h2b   = (bf16*)alloc((size_t)N * 64 * 2);
  bf16*  Wp0   = (bf16*)alloc(256 * 128 * 2);
  bf16*  Wp1   = (bf16*)alloc(128 * 192 * 2);
  bf16*  Wpd   = (bf16*)alloc(64 * 128 * 2);
  float* bi0   = (float*)alloc(128 * 4);
  float* bo0   = (float*)alloc(128 * 4);
  float* bi1   = (float*)alloc(64 * 4);
  float* bo1   = (float*)alloc(64 * 4);
  int*   bcur  = (int*)alloc((size_t)2 * NBMAX * 4);
  int2*  offsPI = (int2*)alloc((size_t)N * 8);
  int2*  offsPO = (int2*)alloc((size_t)N * 8);
  int2*  sI    = (int2*)alloc((size_t)NB * BCAP * 8);
  int2*  sO    = (int2*)alloc((size_t)NB * BCAP * 8);
  int2*  eI    = sI;   // partB output aliases staging (bucket read fully into LDS first)
  int2*  eO    = sO;
  bf16* t1g = aggC;                       // overlay: aggC dead after k_mf01's GEMM0
  bf16* t1r = t1g + (size_t)N * 128;

  (void)hipMemsetAsync(bcur, 0, (size_t)2 * NBMAX * 4, stream);

  dim3 gc(GCX, 2);
  k_partA<<<gc, 256, 0, stream>>>(ei_in, ew_in, ei_ou, ew_ou, E, bcur, sI, sO, NB);
  dim3 gb(NB, 2);
  k_partB<<<gb, 256, 0, stream>>>(bcur, sI, sO, eI, eO, offsPI, offsPO, N);
  k_prep<<<(N * 128 + 255) / 256, 256, 0, stream>>>(
      x, pe, h0bf, N * 128,
      Wmi0, Wmo0, Wsh0, Wmi1, Wmo1, Wsh1, resW, Wd,
      bmi0, bsi0, bmo0, bso0, bmi1, bsi1, bmo1, bso1,
      Wp0, Wp1, Wpd, bi0, bo0, bi1, bo1);

  int ab = (N + 3) / 4;
  int mb = (N + 63) / 64;
  k_agg0<<<ab, 256, 0, stream>>>(h0bf, offsPI, eI, offsPO, eO, cin0, cou0, aggC, N);
  k_mf01<<<mb, 256, 0, stream>>>(aggC, Wp0, Wp1, bi0, bo0, cin0, cou0, h0bf, t1g, t1r, N);

  float* logp = (float*)d_out;
  float* emb  = logp + (size_t)N * 128;
  k_agg1<<<ab, 256, 0, stream>>>(t1g, t1r, offsPI, eI, offsPO, eO, bi1, bo1, resb, cin1, cou1,
                                 h2b, emb, N);
  k_mfd<<<mb, 256, 0, stream>>>(h2b, Wpd, bd, logp, N);
}